// Round 1
// baseline (1233.643 us; speedup 1.0000x reference)
//
#include <hip/hip_runtime.h>
#include <hip/hip_bf16.h>
#include <cmath>

// OctFormer block on MI355X. Round 4: occupancy push.
// R3 profile: MfmaUtil 12%, VALU 26%, HBM 8.5%, Occupancy 23.5% -> latency-bound,
// not roofline-bound. LDS (76.8KB) caps us at 2 blocks/CU; at 256 thr that was
// only 8 waves/CU. R4: 512 threads/block (8 waves), same LDS/tile -> 16 waves/CU
// (50% occupancy). Per-wave work halves (m-half x n-sub split; attention slabs
// split by row-tile). Also: QKV epilogue writes V directly transposed
// (vt[d][key]) so the attention phase loses its LDS transpose round-trip and
// stays fully wave-local (no intra-phase barrier needed).

#define KW    32
#define CD    192
#define NH    6
#define HID   768
#define SCALE 0.17677669529663687f

typedef short short8 __attribute__((ext_vector_type(8)));
typedef float f32x4  __attribute__((ext_vector_type(4)));
typedef unsigned short u16;

// fragment-pool bases (units: 1 fragment = 64 lanes * 8 bf16 = 512 elems)
#define FB_QKV  0     // 36 n-tiles * 6 kb
#define FB_PROJ 216   // 12 * 6
#define FB_MLP1 288   // 48 * 6
#define FB_MLP2 576   // 12 * 24
#define NFRAG   864
#define WS_BYTES (NFRAG * 512 * 2)

__device__ __forceinline__ u16 f2bb(float v) {
  __hip_bfloat16 h = __float2bfloat16(v);
  return *(u16*)&h;
}
__device__ __forceinline__ float bb2f(u16 b) {
  union { float f; unsigned u; } x; x.u = ((unsigned)b) << 16; return x.f;
}

// ---------------- weight pack: f32 row-major -> bf16 B-fragments ----------------
__global__ __launch_bounds__(256) void pack_weights(
    const float* __restrict__ qkv_w, const float* __restrict__ proj_w,
    const float* __restrict__ mlp_w1, const float* __restrict__ mlp_w2,
    u16* __restrict__ ws)
{
  const int idx  = blockIdx.x * 256 + threadIdx.x;   // 864*64 threads
  const int f    = idx >> 6;
  const int lane = idx & 63;
  const float* src; int N, KB, fl;
  if (f < FB_PROJ)      { src = qkv_w;  N = 576; KB = 6;  fl = f; }
  else if (f < FB_MLP1) { src = proj_w; N = 192; KB = 6;  fl = f - FB_PROJ; }
  else if (f < FB_MLP2) { src = mlp_w1; N = 768; KB = 6;  fl = f - FB_MLP1; }
  else                  { src = mlp_w2; N = 192; KB = 24; fl = f - FB_MLP2; }
  const int nt = fl / KB, kb = fl % KB;
  const int k0 = kb * 32 + (lane >> 4) * 8;
  const int n  = nt * 16 + (lane & 15);
  u16* dst = ws + ((size_t)(f * 64 + lane)) * 8;
  #pragma unroll
  for (int j = 0; j < 8; ++j) dst[j] = f2bb(src[(size_t)(k0 + j) * N + n]);
}

// ---------------- fused block kernel (MFMA, 512 thr / 8 waves) ----------------
__global__ __launch_bounds__(512, 4) void octformer_mfma(
    const float* __restrict__ data, const float* __restrict__ mask,
    const int* __restrict__ rel_pos,
    const float* __restrict__ ln1_g, const float* __restrict__ ln1_b,
    const float* __restrict__ qkv_b, const float* __restrict__ rpe_table,
    const float* __restrict__ proj_b,
    const float* __restrict__ ln2_g, const float* __restrict__ ln2_b,
    const float* __restrict__ mlp_b1, const float* __restrict__ mlp_b2,
    const u16* __restrict__ wsb, float* __restrict__ out)
{
  // 64 rows (2 windows) x 192 cols; stride 200 bf16 = 400 B.
  __shared__ __align__(16) u16 s_x[64][200];    // LN out; later proj-out / y-out
  __shared__ __align__(16) u16 s_qkv[64][200];  // q | k | vt per head pair; P overlays q; mlp hidden
  __shared__ __align__(16) u16 s_ao[64][200];   // attention output (proj A)

  const int tid  = threadIdx.x;
  const int n0   = blockIdx.x * 2;
  const size_t base = (size_t)blockIdx.x * (2 * KW * CD);

  const int wv   = tid >> 6;        // wave 0..7
  const int lane = tid & 63;
  const int l15  = lane & 15;
  const int quad = lane >> 4;

  const int rg = tid >> 5;          // elementwise micro-tile: rows rg*4..rg*4+3
  const int c0 = tid & 31;          // cols c0+32*j

  // GEMM phase split: wave = (m-half, n-sub)
  const int mh   = wv >> 2;         // m-tiles {2mh, 2mh+1}
  const int nsub = wv & 3;          // n-tiles {nsub, nsub+4, nsub+8}

  // attention phase split: wave = (row-tile, window, head-parity)
  const int hh   = wv & 1;
  const int w_at = (wv >> 1) & 1;
  const int rth  = wv >> 2;

  const f32x4 zed = {0.f, 0.f, 0.f, 0.f};

  // ---- Phase 1: load data -> res regs, LN1 -> s_x ----
  float res[4][6];
  #pragma unroll
  for (int i = 0; i < 4; ++i) {
    const int r = rg * 4 + i;
    float s = 0.f, q = 0.f;
    #pragma unroll
    for (int j = 0; j < 6; ++j) {
      const float v = data[base + r * CD + c0 + 32 * j];
      res[i][j] = v; s += v; q += v * v;
    }
    #pragma unroll
    for (int m = 16; m >= 1; m >>= 1) { s += __shfl_xor(s, m); q += __shfl_xor(q, m); }
    const float mean = s * (1.0f / CD);
    const float rstd = rsqrtf(q * (1.0f / CD) - mean * mean + 1e-5f);
    #pragma unroll
    for (int j = 0; j < 6; ++j) {
      const int c = c0 + 32 * j;
      s_x[r][c] = f2bb((res[i][j] - mean) * rstd * ln1_g[c] + ln1_b[c]);
    }
  }

  // ---- preload packed RPE indices + mask bit for this wave's attention tile ----
  unsigned pidx[2][4];
  #pragma unroll
  for (int ct = 0; ct < 2; ++ct)
    #pragma unroll
    for (int i = 0; i < 4; ++i) {
      const int r = rth * 16 + quad * 4 + i;
      const int c = ct * 16 + l15;
      const size_t g = ((size_t)(n0 + w_at) * KW + r) * KW + c;
      const int* rp = rel_pos + 3 * g;
      int i0 = rp[0]; i0 = i0 < -25 ? -25 : (i0 > 25 ? 25 : i0); i0 += 25;
      int i1 = rp[1]; i1 = i1 < -25 ? -25 : (i1 > 25 ? 25 : i1); i1 += 76;
      int i2 = rp[2]; i2 = i2 < -25 ? -25 : (i2 > 25 ? 25 : i2); i2 += 127;
      const unsigned mb = (mask[g] < -0.5f) ? (1u << 24) : 0u;
      pidx[ct][i] = (unsigned)i0 | ((unsigned)i1 << 8) | ((unsigned)i2 << 16) | mb;
    }
  __syncthreads();

  // ---- Phase 2: head-pair loop ----
  for (int hp = 0; hp < 3; ++hp) {
    // (a) QKV GEMM for heads {2hp, 2hp+1}: 12 n-tiles x 4 m-tiles over 8 waves
    {
      f32x4 acc[3][2];
      #pragma unroll
      for (int ni = 0; ni < 3; ++ni)
        #pragma unroll
        for (int mi = 0; mi < 2; ++mi) acc[ni][mi] = zed;
      for (int kb = 0; kb < 6; ++kb) {
        short8 a[2];
        #pragma unroll
        for (int mi = 0; mi < 2; ++mi)
          a[mi] = *(const short8*)&s_x[(mh * 2 + mi) * 16 + l15][kb * 32 + quad * 8];
        #pragma unroll
        for (int ni = 0; ni < 3; ++ni) {
          const int lnt = nsub + 4 * ni, part = lnt >> 2, sub = lnt & 3;
          const int gnt = part * 12 + hp * 4 + sub;
          const short8 b = *(const short8*)(wsb + ((size_t)((FB_QKV + gnt * 6 + kb) * 64 + lane)) * 8);
          #pragma unroll
          for (int mi = 0; mi < 2; ++mi)
            acc[ni][mi] = __builtin_amdgcn_mfma_f32_16x16x32_bf16(a[mi], b, acc[ni][mi], 0, 0, 0);
        }
      }
      #pragma unroll
      for (int ni = 0; ni < 3; ++ni) {
        const int lnt = nsub + 4 * ni, part = lnt >> 2, sub = lnt & 3;
        const int gnt = part * 12 + hp * 4 + sub;
        const float bias = qkv_b[gnt * 16 + l15];
        if (part < 2) {                      // q (scaled) and k: row-major
          #pragma unroll
          for (int mi = 0; mi < 2; ++mi)
            #pragma unroll
            for (int i = 0; i < 4; ++i) {
              float v = acc[ni][mi][i] + bias;
              if (part == 0) v *= SCALE;
              s_qkv[(mh * 2 + mi) * 16 + quad * 4 + i][part * 64 + sub * 16 + l15] = f2bb(v);
            }
        } else {                             // v: write TRANSPOSED vt[d][key]
          const int vr = (sub >> 1) * 32 + (sub & 1) * 16 + l15;  // row = hh*32 + d
          #pragma unroll
          for (int mi = 0; mi < 2; ++mi)
            #pragma unroll
            for (int i = 0; i < 4; ++i) {
              const int gr = (mh * 2 + mi) * 16 + quad * 4 + i;   // global key row
              s_qkv[vr][128 + (gr >> 5) * 32 + (gr & 31)] = f2bb(acc[ni][mi][i] + bias);
            }
        }
      }
    }
    __syncthreads();

    // (b) attention: slab (w_at, head h=2hp+hh), row-tile rth; fully wave-local
    {
      const int h = hp * 2 + hh;
      const int rbase = w_at * 32;
      const short8 qf  = *(const short8*)&s_qkv[rbase + rth * 16 + l15][hh * 32 + quad * 8];
      const short8 kf0 = *(const short8*)&s_qkv[rbase + l15][64 + hh * 32 + quad * 8];
      const short8 kf1 = *(const short8*)&s_qkv[rbase + 16 + l15][64 + hh * 32 + quad * 8];
      const f32x4 sa0 = __builtin_amdgcn_mfma_f32_16x16x32_bf16(qf, kf0, zed, 0, 0, 0);
      const f32x4 sa1 = __builtin_amdgcn_mfma_f32_16x16x32_bf16(qf, kf1, zed, 0, 0, 0);
      float S0[4], S1[4];
      #pragma unroll
      for (int i = 0; i < 4; ++i) {
        unsigned p = pidx[0][i];
        float b = rpe_table[(p & 255u) * NH + h]
                + rpe_table[((p >> 8) & 255u) * NH + h]
                + rpe_table[((p >> 16) & 255u) * NH + h];
        if (p >> 24) b -= 1e9f;
        S0[i] = sa0[i] + b;
        p = pidx[1][i];
        b = rpe_table[(p & 255u) * NH + h]
          + rpe_table[((p >> 8) & 255u) * NH + h]
          + rpe_table[((p >> 16) & 255u) * NH + h];
        if (p >> 24) b -= 1e9f;
        S1[i] = sa1[i] + b;
      }
      // softmax over 32 keys (16 lanes x 2 col-tiles); P bf16 into dead q cols
      #pragma unroll
      for (int i = 0; i < 4; ++i) {
        float mx = fmaxf(S0[i], S1[i]);
        #pragma unroll
        for (int m = 8; m >= 1; m >>= 1) mx = fmaxf(mx, __shfl_xor(mx, m));
        const float e0 = __expf(S0[i] - mx);
        const float e1 = __expf(S1[i] - mx);
        float sm = e0 + e1;
        #pragma unroll
        for (int m = 8; m >= 1; m >>= 1) sm += __shfl_xor(sm, m);
        const float inv = 1.0f / sm;
        const int r = rbase + rth * 16 + quad * 4 + i;
        s_qkv[r][hh * 32 + l15]      = f2bb(e0 * inv);
        s_qkv[r][hh * 32 + 16 + l15] = f2bb(e1 * inv);
      }
      // O = P V  (V already transposed in LDS by QKV epilogue)
      const short8 pf  = *(const short8*)&s_qkv[rbase + rth * 16 + l15][hh * 32 + quad * 8];
      const short8 vf0 = *(const short8*)&s_qkv[hh * 32 + l15][128 + w_at * 32 + quad * 8];
      const short8 vf1 = *(const short8*)&s_qkv[hh * 32 + 16 + l15][128 + w_at * 32 + quad * 8];
      const f32x4 o0 = __builtin_amdgcn_mfma_f32_16x16x32_bf16(pf, vf0, zed, 0, 0, 0);
      const f32x4 o1 = __builtin_amdgcn_mfma_f32_16x16x32_bf16(pf, vf1, zed, 0, 0, 0);
      #pragma unroll
      for (int i = 0; i < 4; ++i) {
        const int r = rbase + rth * 16 + quad * 4 + i;
        s_ao[r][h * 32 + l15]      = f2bb(o0[i]);
        s_ao[r][h * 32 + 16 + l15] = f2bb(o1[i]);
      }
    }
    __syncthreads();
  }

  // ---- Phase 3: proj GEMM (A = s_ao) -> s_x (bf16, +bias) ----
  {
    f32x4 acc[3][2];
    #pragma unroll
    for (int ni = 0; ni < 3; ++ni)
      #pragma unroll
      for (int mi = 0; mi < 2; ++mi) acc[ni][mi] = zed;
    for (int kb = 0; kb < 6; ++kb) {
      short8 a[2];
      #pragma unroll
      for (int mi = 0; mi < 2; ++mi)
        a[mi] = *(const short8*)&s_ao[(mh * 2 + mi) * 16 + l15][kb * 32 + quad * 8];
      #pragma unroll
      for (int ni = 0; ni < 3; ++ni) {
        const int nt = nsub + 4 * ni;
        const short8 b = *(const short8*)(wsb + ((size_t)((FB_PROJ + nt * 6 + kb) * 64 + lane)) * 8);
        #pragma unroll
        for (int mi = 0; mi < 2; ++mi)
          acc[ni][mi] = __builtin_amdgcn_mfma_f32_16x16x32_bf16(a[mi], b, acc[ni][mi], 0, 0, 0);
      }
    }
    #pragma unroll
    for (int ni = 0; ni < 3; ++ni) {
      const int nt = nsub + 4 * ni;
      const float bias = proj_b[nt * 16 + l15];
      #pragma unroll
      for (int mi = 0; mi < 2; ++mi)
        #pragma unroll
        for (int i = 0; i < 4; ++i)
          s_x[(mh * 2 + mi) * 16 + quad * 4 + i][nt * 16 + l15] = f2bb(acc[ni][mi][i] + bias);
    }
  }
  __syncthreads();

  // ---- Phase 4: residual add + LN2 (same-element ownership; no race) ----
  #pragma unroll
  for (int i = 0; i < 4; ++i) {
    const int r = rg * 4 + i;
    float s = 0.f, q = 0.f;
    #pragma unroll
    for (int j = 0; j < 6; ++j) {
      res[i][j] += bb2f(s_x[r][c0 + 32 * j]);
      s += res[i][j]; q += res[i][j] * res[i][j];
    }
    #pragma unroll
    for (int m = 16; m >= 1; m >>= 1) { s += __shfl_xor(s, m); q += __shfl_xor(q, m); }
    const float mean = s * (1.0f / CD);
    const float rstd = rsqrtf(q * (1.0f / CD) - mean * mean + 1e-5f);
    #pragma unroll
    for (int j = 0; j < 6; ++j) {
      const int c = c0 + 32 * j;
      s_x[r][c] = f2bb((res[i][j] - mean) * rstd * ln2_g[c] + ln2_b[c]);
    }
  }
  __syncthreads();

  // ---- Phase 5: MLP, hidden 768 in 4 chunks of 192 via s_qkv ----
  {
    f32x4 y[3][2];
    #pragma unroll
    for (int ni = 0; ni < 3; ++ni)
      #pragma unroll
      for (int mi = 0; mi < 2; ++mi) y[ni][mi] = zed;

    for (int cc = 0; cc < 4; ++cc) {
      // mlp1 chunk: gelu(x @ w1 + b1) -> s_qkv bf16
      {
        f32x4 acc[3][2];
        #pragma unroll
        for (int ni = 0; ni < 3; ++ni)
          #pragma unroll
          for (int mi = 0; mi < 2; ++mi) acc[ni][mi] = zed;
        for (int kb = 0; kb < 6; ++kb) {
          short8 a[2];
          #pragma unroll
          for (int mi = 0; mi < 2; ++mi)
            a[mi] = *(const short8*)&s_x[(mh * 2 + mi) * 16 + l15][kb * 32 + quad * 8];
          #pragma unroll
          for (int ni = 0; ni < 3; ++ni) {
            const int gnt = cc * 12 + nsub + 4 * ni;
            const short8 b = *(const short8*)(wsb + ((size_t)((FB_MLP1 + gnt * 6 + kb) * 64 + lane)) * 8);
            #pragma unroll
            for (int mi = 0; mi < 2; ++mi)
              acc[ni][mi] = __builtin_amdgcn_mfma_f32_16x16x32_bf16(a[mi], b, acc[ni][mi], 0, 0, 0);
          }
        }
        #pragma unroll
        for (int ni = 0; ni < 3; ++ni) {
          const int lnt = nsub + 4 * ni;
          const float b1 = mlp_b1[(cc * 12 + lnt) * 16 + l15];
          #pragma unroll
          for (int mi = 0; mi < 2; ++mi)
            #pragma unroll
            for (int i = 0; i < 4; ++i) {
              const float v = acc[ni][mi][i] + b1;
              const float gel = 0.5f * v * (1.0f + erff(v * 0.70710678118654752f));
              s_qkv[(mh * 2 + mi) * 16 + quad * 4 + i][lnt * 16 + l15] = f2bb(gel);
            }
        }
      }
      __syncthreads();

      // mlp2 chunk: y += h_chunk @ w2[cc]
      for (int kb = 0; kb < 6; ++kb) {
        short8 a[2];
        #pragma unroll
        for (int mi = 0; mi < 2; ++mi)
          a[mi] = *(const short8*)&s_qkv[(mh * 2 + mi) * 16 + l15][kb * 32 + quad * 8];
        #pragma unroll
        for (int ni = 0; ni < 3; ++ni) {
          const int nt = nsub + 4 * ni;
          const short8 b = *(const short8*)(wsb + ((size_t)((FB_MLP2 + nt * 24 + cc * 6 + kb) * 64 + lane)) * 8);
          #pragma unroll
          for (int mi = 0; mi < 2; ++mi)
            y[ni][mi] = __builtin_amdgcn_mfma_f32_16x16x32_bf16(a[mi], b, y[ni][mi], 0, 0, 0);
        }
      }
      __syncthreads();
    }

    // y + b2 -> s_x (s_x dead after last mlp1)
    #pragma unroll
    for (int ni = 0; ni < 3; ++ni) {
      const int nt = nsub + 4 * ni;
      const float b2 = mlp_b2[nt * 16 + l15];
      #pragma unroll
      for (int mi = 0; mi < 2; ++mi)
        #pragma unroll
        for (int i = 0; i < 4; ++i)
          s_x[(mh * 2 + mi) * 16 + quad * 4 + i][nt * 16 + l15] = f2bb(y[ni][mi][i] + b2);
    }
  }
  __syncthreads();

  // ---- Phase 6: final residual add + f32 store ----
  #pragma unroll
  for (int i = 0; i < 4; ++i) {
    const int r = rg * 4 + i;
    #pragma unroll
    for (int j = 0; j < 6; ++j)
      out[base + r * CD + c0 + 32 * j] = res[i][j] + bb2f(s_x[r][c0 + 32 * j]);
  }
}

// ---------------- scalar fallback (R2 float path) if ws too small ----------------
__global__ __launch_bounds__(256) void octformer_scalar(
    const float* __restrict__ data, const float* __restrict__ mask, const int* __restrict__ rel_pos,
    const float* __restrict__ ln1_g, const float* __restrict__ ln1_b,
    const float* __restrict__ qkv_w, const float* __restrict__ qkv_b, const float* __restrict__ rpe_table,
    const float* __restrict__ proj_w, const float* __restrict__ proj_b,
    const float* __restrict__ ln2_g, const float* __restrict__ ln2_b,
    const float* __restrict__ mlp_w1, const float* __restrict__ mlp_b1,
    const float* __restrict__ mlp_w2, const float* __restrict__ mlp_b2,
    float* __restrict__ out)
{
  const int n = blockIdx.x, tid = threadIdx.x;
  __shared__ float s_x[KW][CD];
  __shared__ float s_ao[KW][CD];
  __shared__ float s_q[KW][33];
  __shared__ float s_k[KW][33];
  __shared__ float s_p[KW][33];
  const size_t base = (size_t)n * (KW * CD);
  const int r0 = (tid >> 5) << 2, c0 = tid & 31;
  float res[4][6];
  #pragma unroll
  for (int i = 0; i < 4; ++i)
    #pragma unroll
    for (int j = 0; j < 6; ++j) res[i][j] = data[base + (r0 + i) * CD + c0 + 32 * j];
  #pragma unroll
  for (int i = 0; i < 4; ++i) {
    float s = 0.f, q = 0.f;
    #pragma unroll
    for (int j = 0; j < 6; ++j) { s += res[i][j]; q += res[i][j] * res[i][j]; }
    #pragma unroll
    for (int m = 16; m >= 1; m >>= 1) { s += __shfl_xor(s, m); q += __shfl_xor(q, m); }
    const float mean = s / CD, rstd = rsqrtf(q / CD - mean * mean + 1e-5f);
    #pragma unroll
    for (int j = 0; j < 6; ++j) {
      const int c = c0 + 32 * j;
      s_x[r0 + i][c] = (res[i][j] - mean) * rstd * ln1_g[c] + ln1_b[c];
    }
  }
  __syncthreads();
  for (int h = 0; h < NH; ++h) {
    const int qc = h * 32 + c0, kc = CD + h * 32 + c0;
    float aq[4] = {0,0,0,0}, ak[4] = {0,0,0,0};
    for (int kk = 0; kk < CD; ++kk) {
      const float wq = qkv_w[kk * 576 + qc], wk = qkv_w[kk * 576 + kc];
      #pragma unroll
      for (int i = 0; i < 4; ++i) { const float a = s_x[r0 + i][kk]; aq[i] += a * wq; ak[i] += a * wk; }
    }
    #pragma unroll
    for (int i = 0; i < 4; ++i) {
      s_q[r0 + i][c0] = (aq[i] + qkv_b[qc]) * SCALE;
      s_k[r0 + i][c0] = ak[i] + qkv_b[kc];
    }
    __syncthreads();
    {
      float ac[4] = {0,0,0,0};
      #pragma unroll
      for (int d = 0; d < 32; ++d) {
        const float kb = s_k[c0][d];
        #pragma unroll
        for (int i = 0; i < 4; ++i) ac[i] += s_q[r0 + i][d] * kb;
      }
      #pragma unroll
      for (int i = 0; i < 4; ++i) {
        const size_t g = ((size_t)(n * KW + r0 + i)) * KW + c0;
        const int* rp = rel_pos + 3 * g;
        float rpe = 0.f;
        #pragma unroll
        for (int a = 0; a < 3; ++a) {
          int ix = rp[a]; ix = ix < -25 ? -25 : (ix > 25 ? 25 : ix);
          rpe += rpe_table[(ix + 25 + 51 * a) * NH + h];
        }
        s_p[r0 + i][c0] = ac[i] + rpe + mask[g];
      }
    }
    __syncthreads();
    {
      const int r = tid >> 3, sb = tid & 7;
      float v0 = s_p[r][sb], v1 = s_p[r][sb + 8], v2 = s_p[r][sb + 16], v3 = s_p[r][sb + 24];
      float mx = fmaxf(fmaxf(v0, v1), fmaxf(v2, v3));
      mx = fmaxf(mx, __shfl_xor(mx, 1)); mx = fmaxf(mx, __shfl_xor(mx, 2)); mx = fmaxf(mx, __shfl_xor(mx, 4));
      v0 = __expf(v0 - mx); v1 = __expf(v1 - mx); v2 = __expf(v2 - mx); v3 = __expf(v3 - mx);
      float sm = v0 + v1 + v2 + v3;
      sm += __shfl_xor(sm, 1); sm += __shfl_xor(sm, 2); sm += __shfl_xor(sm, 4);
      const float inv = 1.0f / sm;
      s_p[r][sb] = v0 * inv; s_p[r][sb + 8] = v1 * inv; s_p[r][sb + 16] = v2 * inv; s_p[r][sb + 24] = v3 * inv;
    }
    __syncthreads();
    {
      const int vc = 2 * CD + h * 32 + c0;
      float av[4] = {0,0,0,0};
      for (int kk = 0; kk < CD; ++kk) {
        const float wvv = qkv_w[kk * 576 + vc];
        #pragma unroll
        for (int i = 0; i < 4; ++i) av[i] += s_x[r0 + i][kk] * wvv;
      }
      #pragma unroll
      for (int i = 0; i < 4; ++i) s_q[r0 + i][c0] = av[i] + qkv_b[vc];
    }
    __syncthreads();
    {
      float ao[4] = {0,0,0,0};
      #pragma unroll
      for (int j = 0; j < KW; ++j) {
        const float vb = s_q[j][c0];
        #pragma unroll
        for (int i = 0; i < 4; ++i) ao[i] += s_p[r0 + i][j] * vb;
      }
      #pragma unroll
      for (int i = 0; i < 4; ++i) s_ao[r0 + i][h * 32 + c0] = ao[i];
    }
    __syncthreads();
  }
  {
    float acc[4][6];
    #pragma unroll
    for (int j = 0; j < 6; ++j) {
      const float pb = proj_b[c0 + 32 * j];
      #pragma unroll
      for (int i = 0; i < 4; ++i) acc[i][j] = pb;
    }
    for (int kk = 0; kk < CD; ++kk) {
      float a[4];
      #pragma unroll
      for (int i = 0; i < 4; ++i) a[i] = s_ao[r0 + i][kk];
      #pragma unroll
      for (int j = 0; j < 6; ++j) {
        const float w = proj_w[kk * CD + c0 + 32 * j];
        #pragma unroll
        for (int i = 0; i < 4; ++i) acc[i][j] += a[i] * w;
      }
    }
    #pragma unroll
    for (int j = 0; j < 6; ++j)
      #pragma unroll
      for (int i = 0; i < 4; ++i) res[i][j] += acc[i][j];
  }
  __syncthreads();
  #pragma unroll
  for (int i = 0; i < 4; ++i) {
    float s = 0.f, q = 0.f;
    #pragma unroll
    for (int j = 0; j < 6; ++j) { s += res[i][j]; q += res[i][j] * res[i][j]; }
    #pragma unroll
    for (int m = 16; m >= 1; m >>= 1) { s += __shfl_xor(s, m); q += __shfl_xor(q, m); }
    const float mean = s / CD, rstd = rsqrtf(q / CD - mean * mean + 1e-5f);
    #pragma unroll
    for (int j = 0; j < 6; ++j) {
      const int c = c0 + 32 * j;
      s_x[r0 + i][c] = (res[i][j] - mean) * rstd * ln2_g[c] + ln2_b[c];
    }
  }
  __syncthreads();
  {
    float y[4][6];
    #pragma unroll
    for (int j = 0; j < 6; ++j) {
      const float bb = mlp_b2[c0 + 32 * j];
      #pragma unroll
      for (int i = 0; i < 4; ++i) y[i][j] = bb;
    }
    for (int cc = 0; cc < 4; ++cc) {
      {
        float acc[4][6];
        #pragma unroll
        for (int j = 0; j < 6; ++j) {
          const float b1 = mlp_b1[cc * CD + c0 + 32 * j];
          #pragma unroll
          for (int i = 0; i < 4; ++i) acc[i][j] = b1;
        }
        for (int kk = 0; kk < CD; ++kk) {
          float a[4];
          #pragma unroll
          for (int i = 0; i < 4; ++i) a[i] = s_x[r0 + i][kk];
          #pragma unroll
          for (int j = 0; j < 6; ++j) {
            const float w = mlp_w1[kk * HID + cc * CD + c0 + 32 * j];
            #pragma unroll
            for (int i = 0; i < 4; ++i) acc[i][j] += a[i] * w;
          }
        }
        #pragma unroll
        for (int j = 0; j < 6; ++j)
          #pragma unroll
          for (int i = 0; i < 4; ++i) {
            const float x = acc[i][j];
            s_ao[r0 + i][c0 + 32 * j] = 0.5f * x * (1.0f + erff(x * 0.70710678118654752f));
          }
      }
      __syncthreads();
      for (int kk = 0; kk < CD; ++kk) {
        float a[4];
        #pragma unroll
        for (int i = 0; i < 4; ++i) a[i] = s_ao[r0 + i][kk];
        #pragma unroll
        for (int j = 0; j < 6; ++j) {
          const float w = mlp_w2[(cc * CD + kk) * CD + c0 + 32 * j];
          #pragma unroll
          for (int i = 0; i < 4; ++i) y[i][j] += a[i] * w;
        }
      }
      __syncthreads();
    }
    #pragma unroll
    for (int i = 0; i < 4; ++i)
      #pragma unroll
      for (int j = 0; j < 6; ++j)
        out[base + (r0 + i) * CD + c0 + 32 * j] = res[i][j] + y[i][j];
  }
}

extern "C" void kernel_launch(void* const* d_in, const int* in_sizes, int n_in,
                              void* d_out, int out_size, void* d_ws, size_t ws_size,
                              hipStream_t stream) {
  (void)in_sizes; (void)n_in; (void)out_size;
  const float* data   = (const float*)d_in[0];
  const float* maskp  = (const float*)d_in[1];
  const int*   relp   = (const int*)d_in[2];
  const float* ln1g   = (const float*)d_in[3];
  const float* ln1b   = (const float*)d_in[4];
  const float* qkvw   = (const float*)d_in[5];
  const float* qkvb   = (const float*)d_in[6];
  const float* rpet   = (const float*)d_in[7];
  const float* projw  = (const float*)d_in[8];
  const float* projb  = (const float*)d_in[9];
  const float* ln2g   = (const float*)d_in[10];
  const float* ln2b   = (const float*)d_in[11];
  const float* mlpw1  = (const float*)d_in[12];
  const float* mlpb1  = (const float*)d_in[13];
  const float* mlpw2  = (const float*)d_in[14];
  const float* mlpb2  = (const float*)d_in[15];
  float* outp = (float*)d_out;

  if (ws_size >= (size_t)WS_BYTES) {
    u16* ws = (u16*)d_ws;
    pack_weights<<<dim3(NFRAG / 4), dim3(256), 0, stream>>>(qkvw, projw, mlpw1, mlpw2, ws);
    octformer_mfma<<<dim3(4096), dim3(512), 0, stream>>>(
        data, maskp, relp, ln1g, ln1b, qkvb, rpet, projb, ln2g, ln2b, mlpb1, mlpb2, ws, outp);
  } else {
    octformer_scalar<<<dim3(8192), dim3(256), 0, stream>>>(
        data, maskp, relp, ln1g, ln1b, qkvw, qkvb, rpet, projw, projb,
        ln2g, ln2b, mlpw1, mlpb1, mlpw2, mlpb2, outp);
  }
}

// Round 2
// 1224.738 us; speedup vs baseline: 1.0073x; 1.0073x over previous
//
#include <hip/hip_runtime.h>
#include <hip/hip_bf16.h>
#include <cmath>

// OctFormer block on MI355X. Round 5.
// R4 post-mortem: 512 thr + __launch_bounds__(512,4) capped VGPRs at 64 ->
// massive scratch spills (WRITE_SIZE 303->942 MB, FETCH 245->572 MB), dur
// regressed 828->1084 us despite occupancy 43%. Lesson: kernel needs ~128
// VGPRs, so max useful occupancy is 4 waves/SIMD; get there via LDS, not
// thread count.
// R5: 256 thr/block, ONE window per block. LDS 3 x 32x200 u16 = 38.4 KB ->
// 4 blocks/CU = 16 waves/CU = 50% occupancy at <=128 VGPRs (no spill).
// Keeps R4's direct-transposed V write in the QKV epilogue (no separate
// LDS transpose pass in attention).

#define KW    32
#define CD    192
#define NH    6
#define HID   768
#define SCALE 0.17677669529663687f

typedef short short8 __attribute__((ext_vector_type(8)));
typedef float f32x4  __attribute__((ext_vector_type(4)));
typedef unsigned short u16;

// fragment-pool bases (units: 1 fragment = 64 lanes * 8 bf16 = 512 elems)
#define FB_QKV  0     // 36 n-tiles * 6 kb
#define FB_PROJ 216   // 12 * 6
#define FB_MLP1 288   // 48 * 6
#define FB_MLP2 576   // 12 * 24
#define NFRAG   864
#define WS_BYTES (NFRAG * 512 * 2)

__device__ __forceinline__ u16 f2bb(float v) {
  __hip_bfloat16 h = __float2bfloat16(v);
  return *(u16*)&h;
}
__device__ __forceinline__ float bb2f(u16 b) {
  union { float f; unsigned u; } x; x.u = ((unsigned)b) << 16; return x.f;
}

// ---------------- weight pack: f32 row-major -> bf16 B-fragments ----------------
__global__ __launch_bounds__(256) void pack_weights(
    const float* __restrict__ qkv_w, const float* __restrict__ proj_w,
    const float* __restrict__ mlp_w1, const float* __restrict__ mlp_w2,
    u16* __restrict__ ws)
{
  const int idx  = blockIdx.x * 256 + threadIdx.x;   // 864*64 threads
  const int f    = idx >> 6;
  const int lane = idx & 63;
  const float* src; int N, KB, fl;
  if (f < FB_PROJ)      { src = qkv_w;  N = 576; KB = 6;  fl = f; }
  else if (f < FB_MLP1) { src = proj_w; N = 192; KB = 6;  fl = f - FB_PROJ; }
  else if (f < FB_MLP2) { src = mlp_w1; N = 768; KB = 6;  fl = f - FB_MLP1; }
  else                  { src = mlp_w2; N = 192; KB = 24; fl = f - FB_MLP2; }
  const int nt = fl / KB, kb = fl % KB;
  const int k0 = kb * 32 + (lane >> 4) * 8;
  const int n  = nt * 16 + (lane & 15);
  u16* dst = ws + ((size_t)(f * 64 + lane)) * 8;
  #pragma unroll
  for (int j = 0; j < 8; ++j) dst[j] = f2bb(src[(size_t)(k0 + j) * N + n]);
}

// ---------------- fused block kernel (MFMA, 256 thr / 1 window) ----------------
__global__ __launch_bounds__(256, 4) void octformer_mfma(
    const float* __restrict__ data, const float* __restrict__ mask,
    const int* __restrict__ rel_pos,
    const float* __restrict__ ln1_g, const float* __restrict__ ln1_b,
    const float* __restrict__ qkv_b, const float* __restrict__ rpe_table,
    const float* __restrict__ proj_b,
    const float* __restrict__ ln2_g, const float* __restrict__ ln2_b,
    const float* __restrict__ mlp_b1, const float* __restrict__ mlp_b2,
    const u16* __restrict__ wsb, float* __restrict__ out)
{
  // 32 rows (1 window) x 192 cols; stride 200 bf16 = 400 B (16B-aligned rows).
  __shared__ __align__(16) u16 s_x[32][200];    // LN out; later proj-out / y-out
  __shared__ __align__(16) u16 s_qkv[32][200];  // q | k | vt per head pair; P overlays q; mlp hidden
  __shared__ __align__(16) u16 s_ao[32][200];   // attention output (proj A)

  const int tid  = threadIdx.x;
  const int n0   = blockIdx.x;
  const size_t base = (size_t)n0 * (KW * CD);

  const int wv   = tid >> 6;        // wave 0..3
  const int lane = tid & 63;
  const int l15  = lane & 15;
  const int quad = lane >> 4;

  const int rg = tid >> 5;          // elementwise micro-tile: rows rg*4..rg*4+3
  const int c0 = tid & 31;          // cols c0+32*j

  // attention phase split: wave = (row-tile, head-parity)
  const int hh   = wv & 1;
  const int rth  = wv >> 1;

  const f32x4 zed = {0.f, 0.f, 0.f, 0.f};

  // ---- Phase 1: load data -> res regs, LN1 -> s_x ----
  float res[4][6];
  #pragma unroll
  for (int i = 0; i < 4; ++i) {
    const int r = rg * 4 + i;
    float s = 0.f, q = 0.f;
    #pragma unroll
    for (int j = 0; j < 6; ++j) {
      const float v = data[base + r * CD + c0 + 32 * j];
      res[i][j] = v; s += v; q += v * v;
    }
    #pragma unroll
    for (int m = 16; m >= 1; m >>= 1) { s += __shfl_xor(s, m); q += __shfl_xor(q, m); }
    const float mean = s * (1.0f / CD);
    const float rstd = rsqrtf(q * (1.0f / CD) - mean * mean + 1e-5f);
    #pragma unroll
    for (int j = 0; j < 6; ++j) {
      const int c = c0 + 32 * j;
      s_x[r][c] = f2bb((res[i][j] - mean) * rstd * ln1_g[c] + ln1_b[c]);
    }
  }

  // ---- preload packed RPE indices + mask bit for this wave's attention tile ----
  unsigned pidx[2][4];
  #pragma unroll
  for (int ct = 0; ct < 2; ++ct)
    #pragma unroll
    for (int i = 0; i < 4; ++i) {
      const int r = rth * 16 + quad * 4 + i;
      const int c = ct * 16 + l15;
      const size_t g = ((size_t)n0 * KW + r) * KW + c;
      const int* rp = rel_pos + 3 * g;
      int i0 = rp[0]; i0 = i0 < -25 ? -25 : (i0 > 25 ? 25 : i0); i0 += 25;
      int i1 = rp[1]; i1 = i1 < -25 ? -25 : (i1 > 25 ? 25 : i1); i1 += 76;
      int i2 = rp[2]; i2 = i2 < -25 ? -25 : (i2 > 25 ? 25 : i2); i2 += 127;
      const unsigned mb = (mask[g] < -0.5f) ? (1u << 24) : 0u;
      pidx[ct][i] = (unsigned)i0 | ((unsigned)i1 << 8) | ((unsigned)i2 << 16) | mb;
    }
  __syncthreads();

  // ---- Phase 2: head-pair loop ----
  for (int hp = 0; hp < 3; ++hp) {
    // (a) QKV GEMM for heads {2hp, 2hp+1}: 12 n-tiles x 2 m-tiles over 4 waves
    // wave wv handles n-tiles lnt = wv + 4*ni -> part = ni (q/k/v), sub = wv.
    {
      f32x4 acc[3][2];
      #pragma unroll
      for (int ni = 0; ni < 3; ++ni)
        #pragma unroll
        for (int mi = 0; mi < 2; ++mi) acc[ni][mi] = zed;
      for (int kb = 0; kb < 6; ++kb) {
        short8 a[2];
        #pragma unroll
        for (int mi = 0; mi < 2; ++mi)
          a[mi] = *(const short8*)&s_x[mi * 16 + l15][kb * 32 + quad * 8];
        #pragma unroll
        for (int ni = 0; ni < 3; ++ni) {
          const int gnt = ni * 12 + hp * 4 + wv;
          const short8 b = *(const short8*)(wsb + ((size_t)((FB_QKV + gnt * 6 + kb) * 64 + lane)) * 8);
          #pragma unroll
          for (int mi = 0; mi < 2; ++mi)
            acc[ni][mi] = __builtin_amdgcn_mfma_f32_16x16x32_bf16(a[mi], b, acc[ni][mi], 0, 0, 0);
        }
      }
      #pragma unroll
      for (int ni = 0; ni < 3; ++ni) {
        const int gnt = ni * 12 + hp * 4 + wv;
        const float bias = qkv_b[gnt * 16 + l15];
        if (ni < 2) {                        // q (scaled) and k: row-major
          #pragma unroll
          for (int mi = 0; mi < 2; ++mi)
            #pragma unroll
            for (int i = 0; i < 4; ++i) {
              float v = acc[ni][mi][i] + bias;
              if (ni == 0) v *= SCALE;
              s_qkv[mi * 16 + quad * 4 + i][ni * 64 + wv * 16 + l15] = f2bb(v);
            }
        } else {                             // v: write TRANSPOSED vt[d][key]
          const int hv = wv >> 1;            // head parity of this v tile
          const int dr = (wv & 1) * 16 + l15;
          #pragma unroll
          for (int mi = 0; mi < 2; ++mi)
            #pragma unroll
            for (int i = 0; i < 4; ++i) {
              const int key = mi * 16 + quad * 4 + i;
              s_qkv[dr][128 + hv * 32 + key] = f2bb(acc[ni][mi][i] + bias);
            }
        }
      }
    }
    __syncthreads();

    // (b) attention: head h=2hp+hh, Q row-tile rth; fully wave-local
    {
      const int h = hp * 2 + hh;
      const short8 qf  = *(const short8*)&s_qkv[rth * 16 + l15][hh * 32 + quad * 8];
      const short8 kf0 = *(const short8*)&s_qkv[l15][64 + hh * 32 + quad * 8];
      const short8 kf1 = *(const short8*)&s_qkv[16 + l15][64 + hh * 32 + quad * 8];
      const f32x4 sa0 = __builtin_amdgcn_mfma_f32_16x16x32_bf16(qf, kf0, zed, 0, 0, 0);
      const f32x4 sa1 = __builtin_amdgcn_mfma_f32_16x16x32_bf16(qf, kf1, zed, 0, 0, 0);
      float S0[4], S1[4];
      #pragma unroll
      for (int i = 0; i < 4; ++i) {
        unsigned p = pidx[0][i];
        float b = rpe_table[(p & 255u) * NH + h]
                + rpe_table[((p >> 8) & 255u) * NH + h]
                + rpe_table[((p >> 16) & 255u) * NH + h];
        if (p >> 24) b -= 1e9f;
        S0[i] = sa0[i] + b;
        p = pidx[1][i];
        b = rpe_table[(p & 255u) * NH + h]
          + rpe_table[((p >> 8) & 255u) * NH + h]
          + rpe_table[((p >> 16) & 255u) * NH + h];
        if (p >> 24) b -= 1e9f;
        S1[i] = sa1[i] + b;
      }
      // softmax over 32 keys (16 lanes x 2 col-tiles); P bf16 overlays q cols
      #pragma unroll
      for (int i = 0; i < 4; ++i) {
        float mx = fmaxf(S0[i], S1[i]);
        #pragma unroll
        for (int m = 8; m >= 1; m >>= 1) mx = fmaxf(mx, __shfl_xor(mx, m));
        const float e0 = __expf(S0[i] - mx);
        const float e1 = __expf(S1[i] - mx);
        float sm = e0 + e1;
        #pragma unroll
        for (int m = 8; m >= 1; m >>= 1) sm += __shfl_xor(sm, m);
        const float inv = 1.0f / sm;
        const int r = rth * 16 + quad * 4 + i;
        s_qkv[r][hh * 32 + l15]      = f2bb(e0 * inv);
        s_qkv[r][hh * 32 + 16 + l15] = f2bb(e1 * inv);
      }
      // O = P V  (V already transposed in LDS by QKV epilogue)
      const short8 pf  = *(const short8*)&s_qkv[rth * 16 + l15][hh * 32 + quad * 8];
      const short8 vf0 = *(const short8*)&s_qkv[l15][128 + hh * 32 + quad * 8];
      const short8 vf1 = *(const short8*)&s_qkv[16 + l15][128 + hh * 32 + quad * 8];
      const f32x4 o0 = __builtin_amdgcn_mfma_f32_16x16x32_bf16(pf, vf0, zed, 0, 0, 0);
      const f32x4 o1 = __builtin_amdgcn_mfma_f32_16x16x32_bf16(pf, vf1, zed, 0, 0, 0);
      #pragma unroll
      for (int i = 0; i < 4; ++i) {
        const int r = rth * 16 + quad * 4 + i;
        s_ao[r][h * 32 + l15]      = f2bb(o0[i]);
        s_ao[r][h * 32 + 16 + l15] = f2bb(o1[i]);
      }
    }
    __syncthreads();
  }

  // ---- Phase 3: proj GEMM (A = s_ao) -> s_x (bf16, +bias) ----
  {
    f32x4 acc[3][2];
    #pragma unroll
    for (int ni = 0; ni < 3; ++ni)
      #pragma unroll
      for (int mi = 0; mi < 2; ++mi) acc[ni][mi] = zed;
    for (int kb = 0; kb < 6; ++kb) {
      short8 a[2];
      #pragma unroll
      for (int mi = 0; mi < 2; ++mi)
        a[mi] = *(const short8*)&s_ao[mi * 16 + l15][kb * 32 + quad * 8];
      #pragma unroll
      for (int ni = 0; ni < 3; ++ni) {
        const int nt = wv + 4 * ni;
        const short8 b = *(const short8*)(wsb + ((size_t)((FB_PROJ + nt * 6 + kb) * 64 + lane)) * 8);
        #pragma unroll
        for (int mi = 0; mi < 2; ++mi)
          acc[ni][mi] = __builtin_amdgcn_mfma_f32_16x16x32_bf16(a[mi], b, acc[ni][mi], 0, 0, 0);
      }
    }
    #pragma unroll
    for (int ni = 0; ni < 3; ++ni) {
      const int nt = wv + 4 * ni;
      const float bias = proj_b[nt * 16 + l15];
      #pragma unroll
      for (int mi = 0; mi < 2; ++mi)
        #pragma unroll
        for (int i = 0; i < 4; ++i)
          s_x[mi * 16 + quad * 4 + i][nt * 16 + l15] = f2bb(acc[ni][mi][i] + bias);
    }
  }
  __syncthreads();

  // ---- Phase 4: residual add + LN2 (same-element ownership; no race) ----
  #pragma unroll
  for (int i = 0; i < 4; ++i) {
    const int r = rg * 4 + i;
    float s = 0.f, q = 0.f;
    #pragma unroll
    for (int j = 0; j < 6; ++j) {
      res[i][j] += bb2f(s_x[r][c0 + 32 * j]);
      s += res[i][j]; q += res[i][j] * res[i][j];
    }
    #pragma unroll
    for (int m = 16; m >= 1; m >>= 1) { s += __shfl_xor(s, m); q += __shfl_xor(q, m); }
    const float mean = s * (1.0f / CD);
    const float rstd = rsqrtf(q * (1.0f / CD) - mean * mean + 1e-5f);
    #pragma unroll
    for (int j = 0; j < 6; ++j) {
      const int c = c0 + 32 * j;
      s_x[r][c] = f2bb((res[i][j] - mean) * rstd * ln2_g[c] + ln2_b[c]);
    }
  }
  __syncthreads();

  // ---- Phase 5: MLP, hidden 768 in 4 chunks of 192 via s_qkv ----
  {
    f32x4 y[3][2];
    #pragma unroll
    for (int ni = 0; ni < 3; ++ni)
      #pragma unroll
      for (int mi = 0; mi < 2; ++mi) y[ni][mi] = zed;

    for (int cc = 0; cc < 4; ++cc) {
      // mlp1 chunk: gelu(x @ w1 + b1) -> s_qkv bf16
      {
        f32x4 acc[3][2];
        #pragma unroll
        for (int ni = 0; ni < 3; ++ni)
          #pragma unroll
          for (int mi = 0; mi < 2; ++mi) acc[ni][mi] = zed;
        for (int kb = 0; kb < 6; ++kb) {
          short8 a[2];
          #pragma unroll
          for (int mi = 0; mi < 2; ++mi)
            a[mi] = *(const short8*)&s_x[mi * 16 + l15][kb * 32 + quad * 8];
          #pragma unroll
          for (int ni = 0; ni < 3; ++ni) {
            const int gnt = cc * 12 + wv + 4 * ni;
            const short8 b = *(const short8*)(wsb + ((size_t)((FB_MLP1 + gnt * 6 + kb) * 64 + lane)) * 8);
            #pragma unroll
            for (int mi = 0; mi < 2; ++mi)
              acc[ni][mi] = __builtin_amdgcn_mfma_f32_16x16x32_bf16(a[mi], b, acc[ni][mi], 0, 0, 0);
          }
        }
        #pragma unroll
        for (int ni = 0; ni < 3; ++ni) {
          const int lnt = wv + 4 * ni;
          const float b1 = mlp_b1[(cc * 12 + lnt) * 16 + l15];
          #pragma unroll
          for (int mi = 0; mi < 2; ++mi)
            #pragma unroll
            for (int i = 0; i < 4; ++i) {
              const float v = acc[ni][mi][i] + b1;
              const float gel = 0.5f * v * (1.0f + erff(v * 0.70710678118654752f));
              s_qkv[mi * 16 + quad * 4 + i][lnt * 16 + l15] = f2bb(gel);
            }
        }
      }
      __syncthreads();

      // mlp2 chunk: y += h_chunk @ w2[cc]
      for (int kb = 0; kb < 6; ++kb) {
        short8 a[2];
        #pragma unroll
        for (int mi = 0; mi < 2; ++mi)
          a[mi] = *(const short8*)&s_qkv[mi * 16 + l15][kb * 32 + quad * 8];
        #pragma unroll
        for (int ni = 0; ni < 3; ++ni) {
          const int nt = wv + 4 * ni;
          const short8 b = *(const short8*)(wsb + ((size_t)((FB_MLP2 + nt * 24 + cc * 6 + kb) * 64 + lane)) * 8);
          #pragma unroll
          for (int mi = 0; mi < 2; ++mi)
            y[ni][mi] = __builtin_amdgcn_mfma_f32_16x16x32_bf16(a[mi], b, y[ni][mi], 0, 0, 0);
        }
      }
      __syncthreads();
    }

    // y + b2 -> s_x (s_x dead after last mlp1)
    #pragma unroll
    for (int ni = 0; ni < 3; ++ni) {
      const int nt = wv + 4 * ni;
      const float b2 = mlp_b2[nt * 16 + l15];
      #pragma unroll
      for (int mi = 0; mi < 2; ++mi)
        #pragma unroll
        for (int i = 0; i < 4; ++i)
          s_x[mi * 16 + quad * 4 + i][nt * 16 + l15] = f2bb(y[ni][mi][i] + b2);
    }
  }
  __syncthreads();

  // ---- Phase 6: final residual add + f32 store ----
  #pragma unroll
  for (int i = 0; i < 4; ++i) {
    const int r = rg * 4 + i;
    #pragma unroll
    for (int j = 0; j < 6; ++j)
      out[base + r * CD + c0 + 32 * j] = res[i][j] + bb2f(s_x[r][c0 + 32 * j]);
  }
}

// ---------------- scalar fallback (R2 float path) if ws too small ----------------
__global__ __launch_bounds__(256) void octformer_scalar(
    const float* __restrict__ data, const float* __restrict__ mask, const int* __restrict__ rel_pos,
    const float* __restrict__ ln1_g, const float* __restrict__ ln1_b,
    const float* __restrict__ qkv_w, const float* __restrict__ qkv_b, const float* __restrict__ rpe_table,
    const float* __restrict__ proj_w, const float* __restrict__ proj_b,
    const float* __restrict__ ln2_g, const float* __restrict__ ln2_b,
    const float* __restrict__ mlp_w1, const float* __restrict__ mlp_b1,
    const float* __restrict__ mlp_w2, const float* __restrict__ mlp_b2,
    float* __restrict__ out)
{
  const int n = blockIdx.x, tid = threadIdx.x;
  __shared__ float s_x[KW][CD];
  __shared__ float s_ao[KW][CD];
  __shared__ float s_q[KW][33];
  __shared__ float s_k[KW][33];
  __shared__ float s_p[KW][33];
  const size_t base = (size_t)n * (KW * CD);
  const int r0 = (tid >> 5) << 2, c0 = tid & 31;
  float res[4][6];
  #pragma unroll
  for (int i = 0; i < 4; ++i)
    #pragma unroll
    for (int j = 0; j < 6; ++j) res[i][j] = data[base + (r0 + i) * CD + c0 + 32 * j];
  #pragma unroll
  for (int i = 0; i < 4; ++i) {
    float s = 0.f, q = 0.f;
    #pragma unroll
    for (int j = 0; j < 6; ++j) { s += res[i][j]; q += res[i][j] * res[i][j]; }
    #pragma unroll
    for (int m = 16; m >= 1; m >>= 1) { s += __shfl_xor(s, m); q += __shfl_xor(q, m); }
    const float mean = s / CD, rstd = rsqrtf(q / CD - mean * mean + 1e-5f);
    #pragma unroll
    for (int j = 0; j < 6; ++j) {
      const int c = c0 + 32 * j;
      s_x[r0 + i][c] = (res[i][j] - mean) * rstd * ln1_g[c] + ln1_b[c];
    }
  }
  __syncthreads();
  for (int h = 0; h < NH; ++h) {
    const int qc = h * 32 + c0, kc = CD + h * 32 + c0;
    float aq[4] = {0,0,0,0}, ak[4] = {0,0,0,0};
    for (int kk = 0; kk < CD; ++kk) {
      const float wq = qkv_w[kk * 576 + qc], wk = qkv_w[kk * 576 + kc];
      #pragma unroll
      for (int i = 0; i < 4; ++i) { const float a = s_x[r0 + i][kk]; aq[i] += a * wq; ak[i] += a * wk; }
    }
    #pragma unroll
    for (int i = 0; i < 4; ++i) {
      s_q[r0 + i][c0] = (aq[i] + qkv_b[qc]) * SCALE;
      s_k[r0 + i][c0] = ak[i] + qkv_b[kc];
    }
    __syncthreads();
    {
      float ac[4] = {0,0,0,0};
      #pragma unroll
      for (int d = 0; d < 32; ++d) {
        const float kb = s_k[c0][d];
        #pragma unroll
        for (int i = 0; i < 4; ++i) ac[i] += s_q[r0 + i][d] * kb;
      }
      #pragma unroll
      for (int i = 0; i < 4; ++i) {
        const size_t g = ((size_t)(n * KW + r0 + i)) * KW + c0;
        const int* rp = rel_pos + 3 * g;
        float rpe = 0.f;
        #pragma unroll
        for (int a = 0; a < 3; ++a) {
          int ix = rp[a]; ix = ix < -25 ? -25 : (ix > 25 ? 25 : ix);
          rpe += rpe_table[(ix + 25 + 51 * a) * NH + h];
        }
        s_p[r0 + i][c0] = ac[i] + rpe + mask[g];
      }
    }
    __syncthreads();
    {
      const int r = tid >> 3, sb = tid & 7;
      float v0 = s_p[r][sb], v1 = s_p[r][sb + 8], v2 = s_p[r][sb + 16], v3 = s_p[r][sb + 24];
      float mx = fmaxf(fmaxf(v0, v1), fmaxf(v2, v3));
      mx = fmaxf(mx, __shfl_xor(mx, 1)); mx = fmaxf(mx, __shfl_xor(mx, 2)); mx = fmaxf(mx, __shfl_xor(mx, 4));
      v0 = __expf(v0 - mx); v1 = __expf(v1 - mx); v2 = __expf(v2 - mx); v3 = __expf(v3 - mx);
      float sm = v0 + v1 + v2 + v3;
      sm += __shfl_xor(sm, 1); sm += __shfl_xor(sm, 2); sm += __shfl_xor(sm, 4);
      const float inv = 1.0f / sm;
      s_p[r][sb] = v0 * inv; s_p[r][sb + 8] = v1 * inv; s_p[r][sb + 16] = v2 * inv; s_p[r][sb + 24] = v3 * inv;
    }
    __syncthreads();
    {
      const int vc = 2 * CD + h * 32 + c0;
      float av[4] = {0,0,0,0};
      for (int kk = 0; kk < CD; ++kk) {
        const float wvv = qkv_w[kk * 576 + vc];
        #pragma unroll
        for (int i = 0; i < 4; ++i) av[i] += s_x[r0 + i][kk] * wvv;
      }
      #pragma unroll
      for (int i = 0; i < 4; ++i) s_q[r0 + i][c0] = av[i] + qkv_b[vc];
    }
    __syncthreads();
    {
      float ao[4] = {0,0,0,0};
      #pragma unroll
      for (int j = 0; j < KW; ++j) {
        const float vb = s_q[j][c0];
        #pragma unroll
        for (int i = 0; i < 4; ++i) ao[i] += s_p[r0 + i][j] * vb;
      }
      #pragma unroll
      for (int i = 0; i < 4; ++i) s_ao[r0 + i][h * 32 + c0] = ao[i];
    }
    __syncthreads();
  }
  {
    float acc[4][6];
    #pragma unroll
    for (int j = 0; j < 6; ++j) {
      const float pb = proj_b[c0 + 32 * j];
      #pragma unroll
      for (int i = 0; i < 4; ++i) acc[i][j] = pb;
    }
    for (int kk = 0; kk < CD; ++kk) {
      float a[4];
      #pragma unroll
      for (int i = 0; i < 4; ++i) a[i] = s_ao[r0 + i][kk];
      #pragma unroll
      for (int j = 0; j < 6; ++j) {
        const float w = proj_w[kk * CD + c0 + 32 * j];
        #pragma unroll
        for (int i = 0; i < 4; ++i) acc[i][j] += a[i] * w;
      }
    }
    #pragma unroll
    for (int j = 0; j < 6; ++j)
      #pragma unroll
      for (int i = 0; i < 4; ++i) res[i][j] += acc[i][j];
  }
  __syncthreads();
  #pragma unroll
  for (int i = 0; i < 4; ++i) {
    float s = 0.f, q = 0.f;
    #pragma unroll
    for (int j = 0; j < 6; ++j) { s += res[i][j]; q += res[i][j] * res[i][j]; }
    #pragma unroll
    for (int m = 16; m >= 1; m >>= 1) { s += __shfl_xor(s, m); q += __shfl_xor(q, m); }
    const float mean = s / CD, rstd = rsqrtf(q / CD - mean * mean + 1e-5f);
    #pragma unroll
    for (int j = 0; j < 6; ++j) {
      const int c = c0 + 32 * j;
      s_x[r0 + i][c] = (res[i][j] - mean) * rstd * ln2_g[c] + ln2_b[c];
    }
  }
  __syncthreads();
  {
    float y[4][6];
    #pragma unroll
    for (int j = 0; j < 6; ++j) {
      const float bb = mlp_b2[c0 + 32 * j];
      #pragma unroll
      for (int i = 0; i < 4; ++i) y[i][j] = bb;
    }
    for (int cc = 0; cc < 4; ++cc) {
      {
        float acc[4][6];
        #pragma unroll
        for (int j = 0; j < 6; ++j) {
          const float b1 = mlp_b1[cc * CD + c0 + 32 * j];
          #pragma unroll
          for (int i = 0; i < 4; ++i) acc[i][j] = b1;
        }
        for (int kk = 0; kk < CD; ++kk) {
          float a[4];
          #pragma unroll
          for (int i = 0; i < 4; ++i) a[i] = s_x[r0 + i][kk];
          #pragma unroll
          for (int j = 0; j < 6; ++j) {
            const float w = mlp_w1[kk * HID + cc * CD + c0 + 32 * j];
            #pragma unroll
            for (int i = 0; i < 4; ++i) acc[i][j] += a[i] * w;
          }
        }
        #pragma unroll
        for (int j = 0; j < 6; ++j)
          #pragma unroll
          for (int i = 0; i < 4; ++i) {
            const float x = acc[i][j];
            s_ao[r0 + i][c0 + 32 * j] = 0.5f * x * (1.0f + erff(x * 0.70710678118654752f));
          }
      }
      __syncthreads();
      for (int kk = 0; kk < CD; ++kk) {
        float a[4];
        #pragma unroll
        for (int i = 0; i < 4; ++i) a[i] = s_ao[r0 + i][kk];
        #pragma unroll
        for (int j = 0; j < 6; ++j) {
          const float w = mlp_w2[(cc * CD + kk) * CD + c0 + 32 * j];
          #pragma unroll
          for (int i = 0; i < 4; ++i) y[i][j] += a[i] * w;
        }
      }
      __syncthreads();
    }
    #pragma unroll
    for (int i = 0; i < 4; ++i)
      #pragma unroll
      for (int j = 0; j < 6; ++j)
        out[base + (r0 + i) * CD + c0 + 32 * j] = res[i][j] + y[i][j];
  }
}

extern "C" void kernel_launch(void* const* d_in, const int* in_sizes, int n_in,
                              void* d_out, int out_size, void* d_ws, size_t ws_size,
                              hipStream_t stream) {
  (void)in_sizes; (void)n_in; (void)out_size;
  const float* data   = (const float*)d_in[0];
  const float* maskp  = (const float*)d_in[1];
  const int*   relp   = (const int*)d_in[2];
  const float* ln1g   = (const float*)d_in[3];
  const float* ln1b   = (const float*)d_in[4];
  const float* qkvw   = (const float*)d_in[5];
  const float* qkvb   = (const float*)d_in[6];
  const float* rpet   = (const float*)d_in[7];
  const float* projw  = (const float*)d_in[8];
  const float* projb  = (const float*)d_in[9];
  const float* ln2g   = (const float*)d_in[10];
  const float* ln2b   = (const float*)d_in[11];
  const float* mlpw1  = (const float*)d_in[12];
  const float* mlpb1  = (const float*)d_in[13];
  const float* mlpw2  = (const float*)d_in[14];
  const float* mlpb2  = (const float*)d_in[15];
  float* outp = (float*)d_out;

  if (ws_size >= (size_t)WS_BYTES) {
    u16* ws = (u16*)d_ws;
    pack_weights<<<dim3(NFRAG / 4), dim3(256), 0, stream>>>(qkvw, projw, mlpw1, mlpw2, ws);
    octformer_mfma<<<dim3(8192), dim3(256), 0, stream>>>(
        data, maskp, relp, ln1g, ln1b, qkvb, rpet, projb, ln2g, ln2b, mlpb1, mlpb2, ws, outp);
  } else {
    octformer_scalar<<<dim3(8192), dim3(256), 0, stream>>>(
        data, maskp, relp, ln1g, ln1b, qkvw, qkvb, rpet, projw, projb,
        ln2g, ln2b, mlpw1, mlpb1, mlpw2, mlpb2, outp);
  }
}

// Round 3
// 1206.169 us; speedup vs baseline: 1.0228x; 1.0154x over previous
//
#include <hip/hip_runtime.h>
#include <hip/hip_bf16.h>
#include <cmath>

// OctFormer block on MI355X. Round 6.
// R5 post-mortem: spills persisted (FETCH 580/WRITE 958 MB, VGPR_Count 64).
// Empirical rule on this toolchain: __launch_bounds__ 2nd arg 4 => 64-VGPR cap
// => massive scratch spill; 2nd arg 2 (R3) => 128 VGPRs, no spill.
// R6 = R5 body (1 window/block, 38.4 KB LDS, transposed-V epilogue) with
// __launch_bounds__(256, 2). LDS now allows up to 4 blocks/CU; registers
// should land ~128 -> 3-4 blocks/CU without spilling.

#define KW    32
#define CD    192
#define NH    6
#define HID   768
#define SCALE 0.17677669529663687f

typedef short short8 __attribute__((ext_vector_type(8)));
typedef float f32x4  __attribute__((ext_vector_type(4)));
typedef unsigned short u16;

// fragment-pool bases (units: 1 fragment = 64 lanes * 8 bf16 = 512 elems)
#define FB_QKV  0     // 36 n-tiles * 6 kb
#define FB_PROJ 216   // 12 * 6
#define FB_MLP1 288   // 48 * 6
#define FB_MLP2 576   // 12 * 24
#define NFRAG   864
#define WS_BYTES (NFRAG * 512 * 2)

__device__ __forceinline__ u16 f2bb(float v) {
  __hip_bfloat16 h = __float2bfloat16(v);
  return *(u16*)&h;
}
__device__ __forceinline__ float bb2f(u16 b) {
  union { float f; unsigned u; } x; x.u = ((unsigned)b) << 16; return x.f;
}

// ---------------- weight pack: f32 row-major -> bf16 B-fragments ----------------
__global__ __launch_bounds__(256) void pack_weights(
    const float* __restrict__ qkv_w, const float* __restrict__ proj_w,
    const float* __restrict__ mlp_w1, const float* __restrict__ mlp_w2,
    u16* __restrict__ ws)
{
  const int idx  = blockIdx.x * 256 + threadIdx.x;   // 864*64 threads
  const int f    = idx >> 6;
  const int lane = idx & 63;
  const float* src; int N, KB, fl;
  if (f < FB_PROJ)      { src = qkv_w;  N = 576; KB = 6;  fl = f; }
  else if (f < FB_MLP1) { src = proj_w; N = 192; KB = 6;  fl = f - FB_PROJ; }
  else if (f < FB_MLP2) { src = mlp_w1; N = 768; KB = 6;  fl = f - FB_MLP1; }
  else                  { src = mlp_w2; N = 192; KB = 24; fl = f - FB_MLP2; }
  const int nt = fl / KB, kb = fl % KB;
  const int k0 = kb * 32 + (lane >> 4) * 8;
  const int n  = nt * 16 + (lane & 15);
  u16* dst = ws + ((size_t)(f * 64 + lane)) * 8;
  #pragma unroll
  for (int j = 0; j < 8; ++j) dst[j] = f2bb(src[(size_t)(k0 + j) * N + n]);
}

// ---------------- fused block kernel (MFMA, 256 thr / 1 window) ----------------
__global__ __launch_bounds__(256, 2) void octformer_mfma(
    const float* __restrict__ data, const float* __restrict__ mask,
    const int* __restrict__ rel_pos,
    const float* __restrict__ ln1_g, const float* __restrict__ ln1_b,
    const float* __restrict__ qkv_b, const float* __restrict__ rpe_table,
    const float* __restrict__ proj_b,
    const float* __restrict__ ln2_g, const float* __restrict__ ln2_b,
    const float* __restrict__ mlp_b1, const float* __restrict__ mlp_b2,
    const u16* __restrict__ wsb, float* __restrict__ out)
{
  // 32 rows (1 window) x 192 cols; stride 200 bf16 = 400 B (16B-aligned rows).
  __shared__ __align__(16) u16 s_x[32][200];    // LN out; later proj-out / y-out
  __shared__ __align__(16) u16 s_qkv[32][200];  // q | k | vt per head pair; P overlays q; mlp hidden
  __shared__ __align__(16) u16 s_ao[32][200];   // attention output (proj A)

  const int tid  = threadIdx.x;
  const int n0   = blockIdx.x;
  const size_t base = (size_t)n0 * (KW * CD);

  const int wv   = tid >> 6;        // wave 0..3
  const int lane = tid & 63;
  const int l15  = lane & 15;
  const int quad = lane >> 4;

  const int rg = tid >> 5;          // elementwise micro-tile: rows rg*4..rg*4+3
  const int c0 = tid & 31;          // cols c0+32*j

  // attention phase split: wave = (row-tile, head-parity)
  const int hh   = wv & 1;
  const int rth  = wv >> 1;

  const f32x4 zed = {0.f, 0.f, 0.f, 0.f};

  // ---- Phase 1: load data -> res regs, LN1 -> s_x ----
  float res[4][6];
  #pragma unroll
  for (int i = 0; i < 4; ++i) {
    const int r = rg * 4 + i;
    float s = 0.f, q = 0.f;
    #pragma unroll
    for (int j = 0; j < 6; ++j) {
      const float v = data[base + r * CD + c0 + 32 * j];
      res[i][j] = v; s += v; q += v * v;
    }
    #pragma unroll
    for (int m = 16; m >= 1; m >>= 1) { s += __shfl_xor(s, m); q += __shfl_xor(q, m); }
    const float mean = s * (1.0f / CD);
    const float rstd = rsqrtf(q * (1.0f / CD) - mean * mean + 1e-5f);
    #pragma unroll
    for (int j = 0; j < 6; ++j) {
      const int c = c0 + 32 * j;
      s_x[r][c] = f2bb((res[i][j] - mean) * rstd * ln1_g[c] + ln1_b[c]);
    }
  }

  // ---- preload packed RPE indices + mask bit for this wave's attention tile ----
  unsigned pidx[2][4];
  #pragma unroll
  for (int ct = 0; ct < 2; ++ct)
    #pragma unroll
    for (int i = 0; i < 4; ++i) {
      const int r = rth * 16 + quad * 4 + i;
      const int c = ct * 16 + l15;
      const size_t g = ((size_t)n0 * KW + r) * KW + c;
      const int* rp = rel_pos + 3 * g;
      int i0 = rp[0]; i0 = i0 < -25 ? -25 : (i0 > 25 ? 25 : i0); i0 += 25;
      int i1 = rp[1]; i1 = i1 < -25 ? -25 : (i1 > 25 ? 25 : i1); i1 += 76;
      int i2 = rp[2]; i2 = i2 < -25 ? -25 : (i2 > 25 ? 25 : i2); i2 += 127;
      const unsigned mb = (mask[g] < -0.5f) ? (1u << 24) : 0u;
      pidx[ct][i] = (unsigned)i0 | ((unsigned)i1 << 8) | ((unsigned)i2 << 16) | mb;
    }
  __syncthreads();

  // ---- Phase 2: head-pair loop ----
  for (int hp = 0; hp < 3; ++hp) {
    // (a) QKV GEMM for heads {2hp, 2hp+1}: 12 n-tiles x 2 m-tiles over 4 waves
    // wave wv handles n-tiles lnt = wv + 4*ni -> part = ni (q/k/v), sub = wv.
    {
      f32x4 acc[3][2];
      #pragma unroll
      for (int ni = 0; ni < 3; ++ni)
        #pragma unroll
        for (int mi = 0; mi < 2; ++mi) acc[ni][mi] = zed;
      for (int kb = 0; kb < 6; ++kb) {
        short8 a[2];
        #pragma unroll
        for (int mi = 0; mi < 2; ++mi)
          a[mi] = *(const short8*)&s_x[mi * 16 + l15][kb * 32 + quad * 8];
        #pragma unroll
        for (int ni = 0; ni < 3; ++ni) {
          const int gnt = ni * 12 + hp * 4 + wv;
          const short8 b = *(const short8*)(wsb + ((size_t)((FB_QKV + gnt * 6 + kb) * 64 + lane)) * 8);
          #pragma unroll
          for (int mi = 0; mi < 2; ++mi)
            acc[ni][mi] = __builtin_amdgcn_mfma_f32_16x16x32_bf16(a[mi], b, acc[ni][mi], 0, 0, 0);
        }
      }
      #pragma unroll
      for (int ni = 0; ni < 3; ++ni) {
        const int gnt = ni * 12 + hp * 4 + wv;
        const float bias = qkv_b[gnt * 16 + l15];
        if (ni < 2) {                        // q (scaled) and k: row-major
          #pragma unroll
          for (int mi = 0; mi < 2; ++mi)
            #pragma unroll
            for (int i = 0; i < 4; ++i) {
              float v = acc[ni][mi][i] + bias;
              if (ni == 0) v *= SCALE;
              s_qkv[mi * 16 + quad * 4 + i][ni * 64 + wv * 16 + l15] = f2bb(v);
            }
        } else {                             // v: write TRANSPOSED vt[d][key]
          const int hv = wv >> 1;            // head parity of this v tile
          const int dr = (wv & 1) * 16 + l15;
          #pragma unroll
          for (int mi = 0; mi < 2; ++mi)
            #pragma unroll
            for (int i = 0; i < 4; ++i) {
              const int key = mi * 16 + quad * 4 + i;
              s_qkv[dr][128 + hv * 32 + key] = f2bb(acc[ni][mi][i] + bias);
            }
        }
      }
    }
    __syncthreads();

    // (b) attention: head h=2hp+hh, Q row-tile rth; fully wave-local
    {
      const int h = hp * 2 + hh;
      const short8 qf  = *(const short8*)&s_qkv[rth * 16 + l15][hh * 32 + quad * 8];
      const short8 kf0 = *(const short8*)&s_qkv[l15][64 + hh * 32 + quad * 8];
      const short8 kf1 = *(const short8*)&s_qkv[16 + l15][64 + hh * 32 + quad * 8];
      const f32x4 sa0 = __builtin_amdgcn_mfma_f32_16x16x32_bf16(qf, kf0, zed, 0, 0, 0);
      const f32x4 sa1 = __builtin_amdgcn_mfma_f32_16x16x32_bf16(qf, kf1, zed, 0, 0, 0);
      float S0[4], S1[4];
      #pragma unroll
      for (int i = 0; i < 4; ++i) {
        unsigned p = pidx[0][i];
        float b = rpe_table[(p & 255u) * NH + h]
                + rpe_table[((p >> 8) & 255u) * NH + h]
                + rpe_table[((p >> 16) & 255u) * NH + h];
        if (p >> 24) b -= 1e9f;
        S0[i] = sa0[i] + b;
        p = pidx[1][i];
        b = rpe_table[(p & 255u) * NH + h]
          + rpe_table[((p >> 8) & 255u) * NH + h]
          + rpe_table[((p >> 16) & 255u) * NH + h];
        if (p >> 24) b -= 1e9f;
        S1[i] = sa1[i] + b;
      }
      // softmax over 32 keys (16 lanes x 2 col-tiles); P bf16 overlays q cols
      #pragma unroll
      for (int i = 0; i < 4; ++i) {
        float mx = fmaxf(S0[i], S1[i]);
        #pragma unroll
        for (int m = 8; m >= 1; m >>= 1) mx = fmaxf(mx, __shfl_xor(mx, m));
        const float e0 = __expf(S0[i] - mx);
        const float e1 = __expf(S1[i] - mx);
        float sm = e0 + e1;
        #pragma unroll
        for (int m = 8; m >= 1; m >>= 1) sm += __shfl_xor(sm, m);
        const float inv = 1.0f / sm;
        const int r = rth * 16 + quad * 4 + i;
        s_qkv[r][hh * 32 + l15]      = f2bb(e0 * inv);
        s_qkv[r][hh * 32 + 16 + l15] = f2bb(e1 * inv);
      }
      // O = P V  (V already transposed in LDS by QKV epilogue)
      const short8 pf  = *(const short8*)&s_qkv[rth * 16 + l15][hh * 32 + quad * 8];
      const short8 vf0 = *(const short8*)&s_qkv[l15][128 + hh * 32 + quad * 8];
      const short8 vf1 = *(const short8*)&s_qkv[16 + l15][128 + hh * 32 + quad * 8];
      const f32x4 o0 = __builtin_amdgcn_mfma_f32_16x16x32_bf16(pf, vf0, zed, 0, 0, 0);
      const f32x4 o1 = __builtin_amdgcn_mfma_f32_16x16x32_bf16(pf, vf1, zed, 0, 0, 0);
      #pragma unroll
      for (int i = 0; i < 4; ++i) {
        const int r = rth * 16 + quad * 4 + i;
        s_ao[r][h * 32 + l15]      = f2bb(o0[i]);
        s_ao[r][h * 32 + 16 + l15] = f2bb(o1[i]);
      }
    }
    __syncthreads();
  }

  // ---- Phase 3: proj GEMM (A = s_ao) -> s_x (bf16, +bias) ----
  {
    f32x4 acc[3][2];
    #pragma unroll
    for (int ni = 0; ni < 3; ++ni)
      #pragma unroll
      for (int mi = 0; mi < 2; ++mi) acc[ni][mi] = zed;
    for (int kb = 0; kb < 6; ++kb) {
      short8 a[2];
      #pragma unroll
      for (int mi = 0; mi < 2; ++mi)
        a[mi] = *(const short8*)&s_ao[mi * 16 + l15][kb * 32 + quad * 8];
      #pragma unroll
      for (int ni = 0; ni < 3; ++ni) {
        const int nt = wv + 4 * ni;
        const short8 b = *(const short8*)(wsb + ((size_t)((FB_PROJ + nt * 6 + kb) * 64 + lane)) * 8);
        #pragma unroll
        for (int mi = 0; mi < 2; ++mi)
          acc[ni][mi] = __builtin_amdgcn_mfma_f32_16x16x32_bf16(a[mi], b, acc[ni][mi], 0, 0, 0);
      }
    }
    #pragma unroll
    for (int ni = 0; ni < 3; ++ni) {
      const int nt = wv + 4 * ni;
      const float bias = proj_b[nt * 16 + l15];
      #pragma unroll
      for (int mi = 0; mi < 2; ++mi)
        #pragma unroll
        for (int i = 0; i < 4; ++i)
          s_x[mi * 16 + quad * 4 + i][nt * 16 + l15] = f2bb(acc[ni][mi][i] + bias);
    }
  }
  __syncthreads();

  // ---- Phase 4: residual add + LN2 (same-element ownership; no race) ----
  #pragma unroll
  for (int i = 0; i < 4; ++i) {
    const int r = rg * 4 + i;
    float s = 0.f, q = 0.f;
    #pragma unroll
    for (int j = 0; j < 6; ++j) {
      res[i][j] += bb2f(s_x[r][c0 + 32 * j]);
      s += res[i][j]; q += res[i][j] * res[i][j];
    }
    #pragma unroll
    for (int m = 16; m >= 1; m >>= 1) { s += __shfl_xor(s, m); q += __shfl_xor(q, m); }
    const float mean = s * (1.0f / CD);
    const float rstd = rsqrtf(q * (1.0f / CD) - mean * mean + 1e-5f);
    #pragma unroll
    for (int j = 0; j < 6; ++j) {
      const int c = c0 + 32 * j;
      s_x[r][c] = f2bb((res[i][j] - mean) * rstd * ln2_g[c] + ln2_b[c]);
    }
  }
  __syncthreads();

  // ---- Phase 5: MLP, hidden 768 in 4 chunks of 192 via s_qkv ----
  {
    f32x4 y[3][2];
    #pragma unroll
    for (int ni = 0; ni < 3; ++ni)
      #pragma unroll
      for (int mi = 0; mi < 2; ++mi) y[ni][mi] = zed;

    for (int cc = 0; cc < 4; ++cc) {
      // mlp1 chunk: gelu(x @ w1 + b1) -> s_qkv bf16
      {
        f32x4 acc[3][2];
        #pragma unroll
        for (int ni = 0; ni < 3; ++ni)
          #pragma unroll
          for (int mi = 0; mi < 2; ++mi) acc[ni][mi] = zed;
        for (int kb = 0; kb < 6; ++kb) {
          short8 a[2];
          #pragma unroll
          for (int mi = 0; mi < 2; ++mi)
            a[mi] = *(const short8*)&s_x[mi * 16 + l15][kb * 32 + quad * 8];
          #pragma unroll
          for (int ni = 0; ni < 3; ++ni) {
            const int gnt = cc * 12 + wv + 4 * ni;
            const short8 b = *(const short8*)(wsb + ((size_t)((FB_MLP1 + gnt * 6 + kb) * 64 + lane)) * 8);
            #pragma unroll
            for (int mi = 0; mi < 2; ++mi)
              acc[ni][mi] = __builtin_amdgcn_mfma_f32_16x16x32_bf16(a[mi], b, acc[ni][mi], 0, 0, 0);
          }
        }
        #pragma unroll
        for (int ni = 0; ni < 3; ++ni) {
          const int lnt = wv + 4 * ni;
          const float b1 = mlp_b1[(cc * 12 + lnt) * 16 + l15];
          #pragma unroll
          for (int mi = 0; mi < 2; ++mi)
            #pragma unroll
            for (int i = 0; i < 4; ++i) {
              const float v = acc[ni][mi][i] + b1;
              const float gel = 0.5f * v * (1.0f + erff(v * 0.70710678118654752f));
              s_qkv[mi * 16 + quad * 4 + i][lnt * 16 + l15] = f2bb(gel);
            }
        }
      }
      __syncthreads();

      // mlp2 chunk: y += h_chunk @ w2[cc]
      for (int kb = 0; kb < 6; ++kb) {
        short8 a[2];
        #pragma unroll
        for (int mi = 0; mi < 2; ++mi)
          a[mi] = *(const short8*)&s_qkv[mi * 16 + l15][kb * 32 + quad * 8];
        #pragma unroll
        for (int ni = 0; ni < 3; ++ni) {
          const int nt = wv + 4 * ni;
          const short8 b = *(const short8*)(wsb + ((size_t)((FB_MLP2 + nt * 24 + cc * 6 + kb) * 64 + lane)) * 8);
          #pragma unroll
          for (int mi = 0; mi < 2; ++mi)
            y[ni][mi] = __builtin_amdgcn_mfma_f32_16x16x32_bf16(a[mi], b, y[ni][mi], 0, 0, 0);
        }
      }
      __syncthreads();
    }

    // y + b2 -> s_x (s_x dead after last mlp1)
    #pragma unroll
    for (int ni = 0; ni < 3; ++ni) {
      const int nt = wv + 4 * ni;
      const float b2 = mlp_b2[nt * 16 + l15];
      #pragma unroll
      for (int mi = 0; mi < 2; ++mi)
        #pragma unroll
        for (int i = 0; i < 4; ++i)
          s_x[mi * 16 + quad * 4 + i][nt * 16 + l15] = f2bb(y[ni][mi][i] + b2);
    }
  }
  __syncthreads();

  // ---- Phase 6: final residual add + f32 store ----
  #pragma unroll
  for (int i = 0; i < 4; ++i) {
    const int r = rg * 4 + i;
    #pragma unroll
    for (int j = 0; j < 6; ++j)
      out[base + r * CD + c0 + 32 * j] = res[i][j] + bb2f(s_x[r][c0 + 32 * j]);
  }
}

// ---------------- scalar fallback (R2 float path) if ws too small ----------------
__global__ __launch_bounds__(256) void octformer_scalar(
    const float* __restrict__ data, const float* __restrict__ mask, const int* __restrict__ rel_pos,
    const float* __restrict__ ln1_g, const float* __restrict__ ln1_b,
    const float* __restrict__ qkv_w, const float* __restrict__ qkv_b, const float* __restrict__ rpe_table,
    const float* __restrict__ proj_w, const float* __restrict__ proj_b,
    const float* __restrict__ ln2_g, const float* __restrict__ ln2_b,
    const float* __restrict__ mlp_w1, const float* __restrict__ mlp_b1,
    const float* __restrict__ mlp_w2, const float* __restrict__ mlp_b2,
    float* __restrict__ out)
{
  const int n = blockIdx.x, tid = threadIdx.x;
  __shared__ float s_x[KW][CD];
  __shared__ float s_ao[KW][CD];
  __shared__ float s_q[KW][33];
  __shared__ float s_k[KW][33];
  __shared__ float s_p[KW][33];
  const size_t base = (size_t)n * (KW * CD);
  const int r0 = (tid >> 5) << 2, c0 = tid & 31;
  float res[4][6];
  #pragma unroll
  for (int i = 0; i < 4; ++i)
    #pragma unroll
    for (int j = 0; j < 6; ++j) res[i][j] = data[base + (r0 + i) * CD + c0 + 32 * j];
  #pragma unroll
  for (int i = 0; i < 4; ++i) {
    float s = 0.f, q = 0.f;
    #pragma unroll
    for (int j = 0; j < 6; ++j) { s += res[i][j]; q += res[i][j] * res[i][j]; }
    #pragma unroll
    for (int m = 16; m >= 1; m >>= 1) { s += __shfl_xor(s, m); q += __shfl_xor(q, m); }
    const float mean = s / CD, rstd = rsqrtf(q / CD - mean * mean + 1e-5f);
    #pragma unroll
    for (int j = 0; j < 6; ++j) {
      const int c = c0 + 32 * j;
      s_x[r0 + i][c] = (res[i][j] - mean) * rstd * ln1_g[c] + ln1_b[c];
    }
  }
  __syncthreads();
  for (int h = 0; h < NH; ++h) {
    const int qc = h * 32 + c0, kc = CD + h * 32 + c0;
    float aq[4] = {0,0,0,0}, ak[4] = {0,0,0,0};
    for (int kk = 0; kk < CD; ++kk) {
      const float wq = qkv_w[kk * 576 + qc], wk = qkv_w[kk * 576 + kc];
      #pragma unroll
      for (int i = 0; i < 4; ++i) { const float a = s_x[r0 + i][kk]; aq[i] += a * wq; ak[i] += a * wk; }
    }
    #pragma unroll
    for (int i = 0; i < 4; ++i) {
      s_q[r0 + i][c0] = (aq[i] + qkv_b[qc]) * SCALE;
      s_k[r0 + i][c0] = ak[i] + qkv_b[kc];
    }
    __syncthreads();
    {
      float ac[4] = {0,0,0,0};
      #pragma unroll
      for (int d = 0; d < 32; ++d) {
        const float kb = s_k[c0][d];
        #pragma unroll
        for (int i = 0; i < 4; ++i) ac[i] += s_q[r0 + i][d] * kb;
      }
      #pragma unroll
      for (int i = 0; i < 4; ++i) {
        const size_t g = ((size_t)(n * KW + r0 + i)) * KW + c0;
        const int* rp = rel_pos + 3 * g;
        float rpe = 0.f;
        #pragma unroll
        for (int a = 0; a < 3; ++a) {
          int ix = rp[a]; ix = ix < -25 ? -25 : (ix > 25 ? 25 : ix);
          rpe += rpe_table[(ix + 25 + 51 * a) * NH + h];
        }
        s_p[r0 + i][c0] = ac[i] + rpe + mask[g];
      }
    }
    __syncthreads();
    {
      const int r = tid >> 3, sb = tid & 7;
      float v0 = s_p[r][sb], v1 = s_p[r][sb + 8], v2 = s_p[r][sb + 16], v3 = s_p[r][sb + 24];
      float mx = fmaxf(fmaxf(v0, v1), fmaxf(v2, v3));
      mx = fmaxf(mx, __shfl_xor(mx, 1)); mx = fmaxf(mx, __shfl_xor(mx, 2)); mx = fmaxf(mx, __shfl_xor(mx, 4));
      v0 = __expf(v0 - mx); v1 = __expf(v1 - mx); v2 = __expf(v2 - mx); v3 = __expf(v3 - mx);
      float sm = v0 + v1 + v2 + v3;
      sm += __shfl_xor(sm, 1); sm += __shfl_xor(sm, 2); sm += __shfl_xor(sm, 4);
      const float inv = 1.0f / sm;
      s_p[r][sb] = v0 * inv; s_p[r][sb + 8] = v1 * inv; s_p[r][sb + 16] = v2 * inv; s_p[r][sb + 24] = v3 * inv;
    }
    __syncthreads();
    {
      const int vc = 2 * CD + h * 32 + c0;
      float av[4] = {0,0,0,0};
      for (int kk = 0; kk < CD; ++kk) {
        const float wvv = qkv_w[kk * 576 + vc];
        #pragma unroll
        for (int i = 0; i < 4; ++i) av[i] += s_x[r0 + i][kk] * wvv;
      }
      #pragma unroll
      for (int i = 0; i < 4; ++i) s_q[r0 + i][c0] = av[i] + qkv_b[vc];
    }
    __syncthreads();
    {
      float ao[4] = {0,0,0,0};
      #pragma unroll
      for (int j = 0; j < KW; ++j) {
        const float vb = s_q[j][c0];
        #pragma unroll
        for (int i = 0; i < 4; ++i) ao[i] += s_p[r0 + i][j] * vb;
      }
      #pragma unroll
      for (int i = 0; i < 4; ++i) s_ao[r0 + i][h * 32 + c0] = ao[i];
    }
    __syncthreads();
  }
  {
    float acc[4][6];
    #pragma unroll
    for (int j = 0; j < 6; ++j) {
      const float pb = proj_b[c0 + 32 * j];
      #pragma unroll
      for (int i = 0; i < 4; ++i) acc[i][j] = pb;
    }
    for (int kk = 0; kk < CD; ++kk) {
      float a[4];
      #pragma unroll
      for (int i = 0; i < 4; ++i) a[i] = s_ao[r0 + i][kk];
      #pragma unroll
      for (int j = 0; j < 6; ++j) {
        const float w = proj_w[kk * CD + c0 + 32 * j];
        #pragma unroll
        for (int i = 0; i < 4; ++i) acc[i][j] += a[i] * w;
      }
    }
    #pragma unroll
    for (int j = 0; j < 6; ++j)
      #pragma unroll
      for (int i = 0; i < 4; ++i) res[i][j] += acc[i][j];
  }
  __syncthreads();
  #pragma unroll
  for (int i = 0; i < 4; ++i) {
    float s = 0.f, q = 0.f;
    #pragma unroll
    for (int j = 0; j < 6; ++j) { s += res[i][j]; q += res[i][j] * res[i][j]; }
    #pragma unroll
    for (int m = 16; m >= 1; m >>= 1) { s += __shfl_xor(s, m); q += __shfl_xor(q, m); }
    const float mean = s / CD, rstd = rsqrtf(q / CD - mean * mean + 1e-5f);
    #pragma unroll
    for (int j = 0; j < 6; ++j) {
      const int c = c0 + 32 * j;
      s_x[r0 + i][c] = (res[i][j] - mean) * rstd * ln2_g[c] + ln2_b[c];
    }
  }
  __syncthreads();
  {
    float y[4][6];
    #pragma unroll
    for (int j = 0; j < 6; ++j) {
      const float bb = mlp_b2[c0 + 32 * j];
      #pragma unroll
      for (int i = 0; i < 4; ++i) y[i][j] = bb;
    }
    for (int cc = 0; cc < 4; ++cc) {
      {
        float acc[4][6];
        #pragma unroll
        for (int j = 0; j < 6; ++j) {
          const float b1 = mlp_b1[cc * CD + c0 + 32 * j];
          #pragma unroll
          for (int i = 0; i < 4; ++i) acc[i][j] = b1;
        }
        for (int kk = 0; kk < CD; ++kk) {
          float a[4];
          #pragma unroll
          for (int i = 0; i < 4; ++i) a[i] = s_x[r0 + i][kk];
          #pragma unroll
          for (int j = 0; j < 6; ++j) {
            const float w = mlp_w1[kk * HID + cc * CD + c0 + 32 * j];
            #pragma unroll
            for (int i = 0; i < 4; ++i) acc[i][j] += a[i] * w;
          }
        }
        #pragma unroll
        for (int j = 0; j < 6; ++j)
          #pragma unroll
          for (int i = 0; i < 4; ++i) {
            const float x = acc[i][j];
            s_ao[r0 + i][c0 + 32 * j] = 0.5f * x * (1.0f + erff(x * 0.70710678118654752f));
          }
      }
      __syncthreads();
      for (int kk = 0; kk < CD; ++kk) {
        float a[4];
        #pragma unroll
        for (int i = 0; i < 4; ++i) a[i] = s_ao[r0 + i][kk];
        #pragma unroll
        for (int j = 0; j < 6; ++j) {
          const float w = mlp_w2[(cc * CD + kk) * CD + c0 + 32 * j];
          #pragma unroll
          for (int i = 0; i < 4; ++i) y[i][j] += a[i] * w;
        }
      }
      __syncthreads();
    }
    #pragma unroll
    for (int i = 0; i < 4; ++i)
      #pragma unroll
      for (int j = 0; j < 6; ++j)
        out[base + (r0 + i) * CD + c0 + 32 * j] = res[i][j] + y[i][j];
  }
}

extern "C" void kernel_launch(void* const* d_in, const int* in_sizes, int n_in,
                              void* d_out, int out_size, void* d_ws, size_t ws_size,
                              hipStream_t stream) {
  (void)in_sizes; (void)n_in; (void)out_size;
  const float* data   = (const float*)d_in[0];
  const float* maskp  = (const float*)d_in[1];
  const int*   relp   = (const int*)d_in[2];
  const float* ln1g   = (const float*)d_in[3];
  const float* ln1b   = (const float*)d_in[4];
  const float* qkvw   = (const float*)d_in[5];
  const float* qkvb   = (const float*)d_in[6];
  const float* rpet   = (const float*)d_in[7];
  const float* projw  = (const float*)d_in[8];
  const float* projb  = (const float*)d_in[9];
  const float* ln2g   = (const float*)d_in[10];
  const float* ln2b   = (const float*)d_in[11];
  const float* mlpw1  = (const float*)d_in[12];
  const float* mlpb1  = (const float*)d_in[13];
  const float* mlpw2  = (const float*)d_in[14];
  const float* mlpb2  = (const float*)d_in[15];
  float* outp = (float*)d_out;

  if (ws_size >= (size_t)WS_BYTES) {
    u16* ws = (u16*)d_ws;
    pack_weights<<<dim3(NFRAG / 4), dim3(256), 0, stream>>>(qkvw, projw, mlpw1, mlpw2, ws);
    octformer_mfma<<<dim3(8192), dim3(256), 0, stream>>>(
        data, maskp, relp, ln1g, ln1b, qkvb, rpet, projb, ln2g, ln2b, mlpb1, mlpb2, ws, outp);
  } else {
    octformer_scalar<<<dim3(8192), dim3(256), 0, stream>>>(
        data, maskp, relp, ln1g, ln1b, qkvw, qkvb, rpet, projw, projb,
        ln2g, ln2b, mlpw1, mlpb1, mlpw2, mlpb2, outp);
  }
}

// Round 4
// 1136.330 us; speedup vs baseline: 1.0856x; 1.0615x over previous
//
#include <hip/hip_runtime.h>
#include <hip/hip_bf16.h>
#include <cmath>

// OctFormer block on MI355X. Round 7: two-kernel split.
// R6 post-mortem: no spill (VGPR 88) but occupancy stuck at 24%. Occupancy tier
// law reconstructed from R3-R6: waves/CU steps at total regs (arch+AGPR) =
// {<=64:32, <=128:16, <=256:8}. R6 = 88 arch + ~48 agpr = 136 -> 8-wave tier.
// Fused kernel can't fit the 16-wave tier: residual regs + dual accumulators.
// R7: split at the attention/MLP seam.
//   A: LN1+QKV+attn+proj+residual -> x2 (f32, into out). No y-acc, no MLP.
//      Residual via data re-read at epilogue (no res regs). 2-window tile,
//      512 thr, 76.8 KB LDS -> 2 blocks/CU, 16 waves if total<=128.
//   B: LN2+MLP+residual RMW on out. Row-wise only, 64 rows/block, 512 thr,
//      51.2 KB LDS. No attention state. Target 16-wave tier too.

#define KW    32
#define CD    192
#define NH    6
#define HID   768
#define SCALE 0.17677669529663687f

typedef short short8 __attribute__((ext_vector_type(8)));
typedef float f32x4  __attribute__((ext_vector_type(4)));
typedef unsigned short u16;

// fragment-pool bases (units: 1 fragment = 64 lanes * 8 bf16 = 512 elems)
#define FB_QKV  0     // 36 n-tiles * 6 kb
#define FB_PROJ 216   // 12 * 6
#define FB_MLP1 288   // 48 * 6
#define FB_MLP2 576   // 12 * 24
#define NFRAG   864
#define WS_BYTES (NFRAG * 512 * 2)

__device__ __forceinline__ u16 f2bb(float v) {
  __hip_bfloat16 h = __float2bfloat16(v);
  return *(u16*)&h;
}
__device__ __forceinline__ float bb2f(u16 b) {
  union { float f; unsigned u; } x; x.u = ((unsigned)b) << 16; return x.f;
}

// ---------------- weight pack: f32 row-major -> bf16 B-fragments ----------------
__global__ __launch_bounds__(256) void pack_weights(
    const float* __restrict__ qkv_w, const float* __restrict__ proj_w,
    const float* __restrict__ mlp_w1, const float* __restrict__ mlp_w2,
    u16* __restrict__ ws)
{
  const int idx  = blockIdx.x * 256 + threadIdx.x;   // 864*64 threads
  const int f    = idx >> 6;
  const int lane = idx & 63;
  const float* src; int N, KB, fl;
  if (f < FB_PROJ)      { src = qkv_w;  N = 576; KB = 6;  fl = f; }
  else if (f < FB_MLP1) { src = proj_w; N = 192; KB = 6;  fl = f - FB_PROJ; }
  else if (f < FB_MLP2) { src = mlp_w1; N = 768; KB = 6;  fl = f - FB_MLP1; }
  else                  { src = mlp_w2; N = 192; KB = 24; fl = f - FB_MLP2; }
  const int nt = fl / KB, kb = fl % KB;
  const int k0 = kb * 32 + (lane >> 4) * 8;
  const int n  = nt * 16 + (lane & 15);
  u16* dst = ws + ((size_t)(f * 64 + lane)) * 8;
  #pragma unroll
  for (int j = 0; j < 8; ++j) dst[j] = f2bb(src[(size_t)(k0 + j) * N + n]);
}

// ---------------- kernel A: LN1 + QKV + attention + proj + residual -> x2 ----------------
__global__ __launch_bounds__(512) void octformer_attn(
    const float* __restrict__ data, const float* __restrict__ mask,
    const int* __restrict__ rel_pos,
    const float* __restrict__ ln1_g, const float* __restrict__ ln1_b,
    const float* __restrict__ qkv_b, const float* __restrict__ rpe_table,
    const float* __restrict__ proj_b,
    const u16* __restrict__ wsb, float* __restrict__ x2)
{
  // 64 rows (2 windows) x 192 cols; stride 200 bf16 = 400 B.
  __shared__ __align__(16) u16 s_x[64][200];    // LN1 out; later proj-out
  __shared__ __align__(16) u16 s_qkv[64][200];  // q | k | vt; P overlays q
  __shared__ __align__(16) u16 s_ao[64][200];   // attention output (proj A)

  const int tid  = threadIdx.x;
  const int n0   = blockIdx.x * 2;
  const size_t base = (size_t)blockIdx.x * (2 * KW * CD);

  const int wv   = tid >> 6;        // wave 0..7
  const int lane = tid & 63;
  const int l15  = lane & 15;
  const int quad = lane >> 4;

  const int rg = tid >> 5;          // elementwise rows rg*4..rg*4+3
  const int c0 = tid & 31;

  const int mh   = wv >> 2;         // GEMM: m-tiles {2mh, 2mh+1}
  const int nsub = wv & 3;          // GEMM: n-tiles {nsub, nsub+4, nsub+8}

  const int hh   = wv & 1;          // attention: head parity
  const int w_at = (wv >> 1) & 1;   // attention: window
  const int rth  = wv >> 2;         // attention: q row-tile

  const f32x4 zed = {0.f, 0.f, 0.f, 0.f};

  // ---- Phase 1: LN1 -> s_x (no residual registers kept) ----
  #pragma unroll
  for (int i = 0; i < 4; ++i) {
    const int r = rg * 4 + i;
    float v[6]; float s = 0.f, q = 0.f;
    #pragma unroll
    for (int j = 0; j < 6; ++j) {
      v[j] = data[base + r * CD + c0 + 32 * j];
      s += v[j]; q += v[j] * v[j];
    }
    #pragma unroll
    for (int m = 16; m >= 1; m >>= 1) { s += __shfl_xor(s, m); q += __shfl_xor(q, m); }
    const float mean = s * (1.0f / CD);
    const float rstd = rsqrtf(q * (1.0f / CD) - mean * mean + 1e-5f);
    #pragma unroll
    for (int j = 0; j < 6; ++j) {
      const int c = c0 + 32 * j;
      s_x[r][c] = f2bb((v[j] - mean) * rstd * ln1_g[c] + ln1_b[c]);
    }
  }

  // ---- preload packed RPE indices + mask bit for this wave's attention tile ----
  unsigned pidx[2][4];
  #pragma unroll
  for (int ct = 0; ct < 2; ++ct)
    #pragma unroll
    for (int i = 0; i < 4; ++i) {
      const int r = rth * 16 + quad * 4 + i;
      const int c = ct * 16 + l15;
      const size_t g = ((size_t)(n0 + w_at) * KW + r) * KW + c;
      const int* rp = rel_pos + 3 * g;
      int i0 = rp[0]; i0 = i0 < -25 ? -25 : (i0 > 25 ? 25 : i0); i0 += 25;
      int i1 = rp[1]; i1 = i1 < -25 ? -25 : (i1 > 25 ? 25 : i1); i1 += 76;
      int i2 = rp[2]; i2 = i2 < -25 ? -25 : (i2 > 25 ? 25 : i2); i2 += 127;
      const unsigned mb = (mask[g] < -0.5f) ? (1u << 24) : 0u;
      pidx[ct][i] = (unsigned)i0 | ((unsigned)i1 << 8) | ((unsigned)i2 << 16) | mb;
    }
  __syncthreads();

  // ---- Phase 2: head-pair loop ----
  for (int hp = 0; hp < 3; ++hp) {
    // (a) QKV GEMM for heads {2hp, 2hp+1}: 12 n-tiles x 4 m-tiles over 8 waves
    {
      f32x4 acc[3][2];
      #pragma unroll
      for (int ni = 0; ni < 3; ++ni)
        #pragma unroll
        for (int mi = 0; mi < 2; ++mi) acc[ni][mi] = zed;
      for (int kb = 0; kb < 6; ++kb) {
        short8 a[2];
        #pragma unroll
        for (int mi = 0; mi < 2; ++mi)
          a[mi] = *(const short8*)&s_x[(mh * 2 + mi) * 16 + l15][kb * 32 + quad * 8];
        #pragma unroll
        for (int ni = 0; ni < 3; ++ni) {
          const int gnt = ni * 12 + hp * 4 + nsub;
          const short8 b = *(const short8*)(wsb + ((size_t)((FB_QKV + gnt * 6 + kb) * 64 + lane)) * 8);
          #pragma unroll
          for (int mi = 0; mi < 2; ++mi)
            acc[ni][mi] = __builtin_amdgcn_mfma_f32_16x16x32_bf16(a[mi], b, acc[ni][mi], 0, 0, 0);
        }
      }
      #pragma unroll
      for (int ni = 0; ni < 3; ++ni) {
        const int gnt = ni * 12 + hp * 4 + nsub;
        const float bias = qkv_b[gnt * 16 + l15];
        if (ni < 2) {                        // q (scaled) and k: row-major
          #pragma unroll
          for (int mi = 0; mi < 2; ++mi)
            #pragma unroll
            for (int i = 0; i < 4; ++i) {
              float v = acc[ni][mi][i] + bias;
              if (ni == 0) v *= SCALE;
              s_qkv[(mh * 2 + mi) * 16 + quad * 4 + i][ni * 64 + nsub * 16 + l15] = f2bb(v);
            }
        } else {                             // v: write TRANSPOSED vt[d][key]
          const int vr = (nsub >> 1) * 32 + (nsub & 1) * 16 + l15;  // row = hv*32 + d
          #pragma unroll
          for (int mi = 0; mi < 2; ++mi)
            #pragma unroll
            for (int i = 0; i < 4; ++i) {
              const int gr = (mh * 2 + mi) * 16 + quad * 4 + i;     // global key row
              s_qkv[vr][128 + (gr >> 5) * 32 + (gr & 31)] = f2bb(acc[ni][mi][i] + bias);
            }
        }
      }
    }
    __syncthreads();

    // (b) attention: slab (w_at, head h=2hp+hh), row-tile rth; wave-local
    {
      const int h = hp * 2 + hh;
      const int rbase = w_at * 32;
      const short8 qf  = *(const short8*)&s_qkv[rbase + rth * 16 + l15][hh * 32 + quad * 8];
      const short8 kf0 = *(const short8*)&s_qkv[rbase + l15][64 + hh * 32 + quad * 8];
      const short8 kf1 = *(const short8*)&s_qkv[rbase + 16 + l15][64 + hh * 32 + quad * 8];
      const f32x4 sa0 = __builtin_amdgcn_mfma_f32_16x16x32_bf16(qf, kf0, zed, 0, 0, 0);
      const f32x4 sa1 = __builtin_amdgcn_mfma_f32_16x16x32_bf16(qf, kf1, zed, 0, 0, 0);
      float S0[4], S1[4];
      #pragma unroll
      for (int i = 0; i < 4; ++i) {
        unsigned p = pidx[0][i];
        float b = rpe_table[(p & 255u) * NH + h]
                + rpe_table[((p >> 8) & 255u) * NH + h]
                + rpe_table[((p >> 16) & 255u) * NH + h];
        if (p >> 24) b -= 1e9f;
        S0[i] = sa0[i] + b;
        p = pidx[1][i];
        b = rpe_table[(p & 255u) * NH + h]
          + rpe_table[((p >> 8) & 255u) * NH + h]
          + rpe_table[((p >> 16) & 255u) * NH + h];
        if (p >> 24) b -= 1e9f;
        S1[i] = sa1[i] + b;
      }
      // softmax over 32 keys; P bf16 overlays q cols (own slab region only)
      #pragma unroll
      for (int i = 0; i < 4; ++i) {
        float mx = fmaxf(S0[i], S1[i]);
        #pragma unroll
        for (int m = 8; m >= 1; m >>= 1) mx = fmaxf(mx, __shfl_xor(mx, m));
        const float e0 = __expf(S0[i] - mx);
        const float e1 = __expf(S1[i] - mx);
        float sm = e0 + e1;
        #pragma unroll
        for (int m = 8; m >= 1; m >>= 1) sm += __shfl_xor(sm, m);
        const float inv = 1.0f / sm;
        const int r = rbase + rth * 16 + quad * 4 + i;
        s_qkv[r][hh * 32 + l15]      = f2bb(e0 * inv);
        s_qkv[r][hh * 32 + 16 + l15] = f2bb(e1 * inv);
      }
      // O = P V  (V already transposed in LDS by QKV epilogue)
      const short8 pf  = *(const short8*)&s_qkv[rbase + rth * 16 + l15][hh * 32 + quad * 8];
      const short8 vf0 = *(const short8*)&s_qkv[hh * 32 + l15][128 + w_at * 32 + quad * 8];
      const short8 vf1 = *(const short8*)&s_qkv[hh * 32 + 16 + l15][128 + w_at * 32 + quad * 8];
      const f32x4 o0 = __builtin_amdgcn_mfma_f32_16x16x32_bf16(pf, vf0, zed, 0, 0, 0);
      const f32x4 o1 = __builtin_amdgcn_mfma_f32_16x16x32_bf16(pf, vf1, zed, 0, 0, 0);
      #pragma unroll
      for (int i = 0; i < 4; ++i) {
        const int r = rbase + rth * 16 + quad * 4 + i;
        s_ao[r][h * 32 + l15]      = f2bb(o0[i]);
        s_ao[r][h * 32 + 16 + l15] = f2bb(o1[i]);
      }
    }
    __syncthreads();
  }

  // ---- Phase 3: proj GEMM (A = s_ao) -> s_x (bf16, +bias) ----
  {
    f32x4 acc[3][2];
    #pragma unroll
    for (int ni = 0; ni < 3; ++ni)
      #pragma unroll
      for (int mi = 0; mi < 2; ++mi) acc[ni][mi] = zed;
    for (int kb = 0; kb < 6; ++kb) {
      short8 a[2];
      #pragma unroll
      for (int mi = 0; mi < 2; ++mi)
        a[mi] = *(const short8*)&s_ao[(mh * 2 + mi) * 16 + l15][kb * 32 + quad * 8];
      #pragma unroll
      for (int ni = 0; ni < 3; ++ni) {
        const int nt = nsub + 4 * ni;
        const short8 b = *(const short8*)(wsb + ((size_t)((FB_PROJ + nt * 6 + kb) * 64 + lane)) * 8);
        #pragma unroll
        for (int mi = 0; mi < 2; ++mi)
          acc[ni][mi] = __builtin_amdgcn_mfma_f32_16x16x32_bf16(a[mi], b, acc[ni][mi], 0, 0, 0);
      }
    }
    #pragma unroll
    for (int ni = 0; ni < 3; ++ni) {
      const int nt = nsub + 4 * ni;
      const float bias = proj_b[nt * 16 + l15];
      #pragma unroll
      for (int mi = 0; mi < 2; ++mi)
        #pragma unroll
        for (int i = 0; i < 4; ++i)
          s_x[(mh * 2 + mi) * 16 + quad * 4 + i][nt * 16 + l15] = f2bb(acc[ni][mi][i] + bias);
    }
  }
  __syncthreads();

  // ---- epilogue: x2 = data (re-read) + proj_out ----
  #pragma unroll
  for (int i = 0; i < 4; ++i) {
    const int r = rg * 4 + i;
    #pragma unroll
    for (int j = 0; j < 6; ++j) {
      const int c = c0 + 32 * j;
      x2[base + r * CD + c] = data[base + r * CD + c] + bb2f(s_x[r][c]);
    }
  }
}

// ---------------- kernel B: LN2 + MLP + residual (RMW on io = x2 -> final) ----------------
__global__ __launch_bounds__(512) void octformer_mlp(
    const float* __restrict__ ln2_g, const float* __restrict__ ln2_b,
    const float* __restrict__ mlp_b1, const float* __restrict__ mlp_b2,
    const u16* __restrict__ wsb, float* __restrict__ io)
{
  __shared__ __align__(16) u16 s_x[64][200];   // LN2 out
  __shared__ __align__(16) u16 s_h[64][200];   // gelu hidden chunk

  const int tid  = threadIdx.x;
  const size_t base = (size_t)blockIdx.x * (64 * CD);

  const int wv   = tid >> 6;
  const int lane = tid & 63;
  const int l15  = lane & 15;
  const int quad = lane >> 4;

  const int rg = tid >> 5;
  const int c0 = tid & 31;

  const int mh   = wv >> 2;
  const int nsub = wv & 3;

  const f32x4 zed = {0.f, 0.f, 0.f, 0.f};

  // ---- Phase 1: LN2(x2) -> s_x ----
  #pragma unroll
  for (int i = 0; i < 4; ++i) {
    const int r = rg * 4 + i;
    float v[6]; float s = 0.f, q = 0.f;
    #pragma unroll
    for (int j = 0; j < 6; ++j) {
      v[j] = io[base + r * CD + c0 + 32 * j];
      s += v[j]; q += v[j] * v[j];
    }
    #pragma unroll
    for (int m = 16; m >= 1; m >>= 1) { s += __shfl_xor(s, m); q += __shfl_xor(q, m); }
    const float mean = s * (1.0f / CD);
    const float rstd = rsqrtf(q * (1.0f / CD) - mean * mean + 1e-5f);
    #pragma unroll
    for (int j = 0; j < 6; ++j) {
      const int c = c0 + 32 * j;
      s_x[r][c] = f2bb((v[j] - mean) * rstd * ln2_g[c] + ln2_b[c]);
    }
  }
  __syncthreads();

  // ---- Phase 2: MLP, hidden 768 in 4 chunks of 192 ----
  f32x4 y[3][2];
  #pragma unroll
  for (int ni = 0; ni < 3; ++ni)
    #pragma unroll
    for (int mi = 0; mi < 2; ++mi) y[ni][mi] = zed;

  for (int cc = 0; cc < 4; ++cc) {
    // mlp1 chunk: gelu(x @ w1 + b1) -> s_h bf16
    {
      f32x4 acc[3][2];
      #pragma unroll
      for (int ni = 0; ni < 3; ++ni)
        #pragma unroll
        for (int mi = 0; mi < 2; ++mi) acc[ni][mi] = zed;
      for (int kb = 0; kb < 6; ++kb) {
        short8 a[2];
        #pragma unroll
        for (int mi = 0; mi < 2; ++mi)
          a[mi] = *(const short8*)&s_x[(mh * 2 + mi) * 16 + l15][kb * 32 + quad * 8];
        #pragma unroll
        for (int ni = 0; ni < 3; ++ni) {
          const int gnt = cc * 12 + nsub + 4 * ni;
          const short8 b = *(const short8*)(wsb + ((size_t)((FB_MLP1 + gnt * 6 + kb) * 64 + lane)) * 8);
          #pragma unroll
          for (int mi = 0; mi < 2; ++mi)
            acc[ni][mi] = __builtin_amdgcn_mfma_f32_16x16x32_bf16(a[mi], b, acc[ni][mi], 0, 0, 0);
        }
      }
      #pragma unroll
      for (int ni = 0; ni < 3; ++ni) {
        const int lnt = nsub + 4 * ni;
        const float b1 = mlp_b1[(cc * 12 + lnt) * 16 + l15];
        #pragma unroll
        for (int mi = 0; mi < 2; ++mi)
          #pragma unroll
          for (int i = 0; i < 4; ++i) {
            const float v = acc[ni][mi][i] + b1;
            const float gel = 0.5f * v * (1.0f + erff(v * 0.70710678118654752f));
            s_h[(mh * 2 + mi) * 16 + quad * 4 + i][lnt * 16 + l15] = f2bb(gel);
          }
      }
    }
    __syncthreads();

    // mlp2 chunk: y += h_chunk @ w2[cc]
    for (int kb = 0; kb < 6; ++kb) {
      short8 a[2];
      #pragma unroll
      for (int mi = 0; mi < 2; ++mi)
        a[mi] = *(const short8*)&s_h[(mh * 2 + mi) * 16 + l15][kb * 32 + quad * 8];
      #pragma unroll
      for (int ni = 0; ni < 3; ++ni) {
        const int nt = nsub + 4 * ni;
        const short8 b = *(const short8*)(wsb + ((size_t)((FB_MLP2 + nt * 24 + cc * 6 + kb) * 64 + lane)) * 8);
        #pragma unroll
        for (int mi = 0; mi < 2; ++mi)
          y[ni][mi] = __builtin_amdgcn_mfma_f32_16x16x32_bf16(a[mi], b, y[ni][mi], 0, 0, 0);
      }
    }
    __syncthreads();
  }

  // ---- epilogue: io = x2 + y + b2 (direct global RMW in MFMA layout) ----
  #pragma unroll
  for (int ni = 0; ni < 3; ++ni) {
    const int nt = nsub + 4 * ni;
    const float b2 = mlp_b2[nt * 16 + l15];
    #pragma unroll
    for (int mi = 0; mi < 2; ++mi)
      #pragma unroll
      for (int i = 0; i < 4; ++i) {
        const size_t g = base + (size_t)((mh * 2 + mi) * 16 + quad * 4 + i) * CD + nt * 16 + l15;
        io[g] = io[g] + y[ni][mi][i] + b2;
      }
  }
}

// ---------------- scalar fallback (R2 float path) if ws too small ----------------
__global__ __launch_bounds__(256) void octformer_scalar(
    const float* __restrict__ data, const float* __restrict__ mask, const int* __restrict__ rel_pos,
    const float* __restrict__ ln1_g, const float* __restrict__ ln1_b,
    const float* __restrict__ qkv_w, const float* __restrict__ qkv_b, const float* __restrict__ rpe_table,
    const float* __restrict__ proj_w, const float* __restrict__ proj_b,
    const float* __restrict__ ln2_g, const float* __restrict__ ln2_b,
    const float* __restrict__ mlp_w1, const float* __restrict__ mlp_b1,
    const float* __restrict__ mlp_w2, const float* __restrict__ mlp_b2,
    float* __restrict__ out)
{
  const int n = blockIdx.x, tid = threadIdx.x;
  __shared__ float s_x[KW][CD];
  __shared__ float s_ao[KW][CD];
  __shared__ float s_q[KW][33];
  __shared__ float s_k[KW][33];
  __shared__ float s_p[KW][33];
  const size_t base = (size_t)n * (KW * CD);
  const int r0 = (tid >> 5) << 2, c0 = tid & 31;
  float res[4][6];
  #pragma unroll
  for (int i = 0; i < 4; ++i)
    #pragma unroll
    for (int j = 0; j < 6; ++j) res[i][j] = data[base + (r0 + i) * CD + c0 + 32 * j];
  #pragma unroll
  for (int i = 0; i < 4; ++i) {
    float s = 0.f, q = 0.f;
    #pragma unroll
    for (int j = 0; j < 6; ++j) { s += res[i][j]; q += res[i][j] * res[i][j]; }
    #pragma unroll
    for (int m = 16; m >= 1; m >>= 1) { s += __shfl_xor(s, m); q += __shfl_xor(q, m); }
    const float mean = s / CD, rstd = rsqrtf(q / CD - mean * mean + 1e-5f);
    #pragma unroll
    for (int j = 0; j < 6; ++j) {
      const int c = c0 + 32 * j;
      s_x[r0 + i][c] = (res[i][j] - mean) * rstd * ln1_g[c] + ln1_b[c];
    }
  }
  __syncthreads();
  for (int h = 0; h < NH; ++h) {
    const int qc = h * 32 + c0, kc = CD + h * 32 + c0;
    float aq[4] = {0,0,0,0}, ak[4] = {0,0,0,0};
    for (int kk = 0; kk < CD; ++kk) {
      const float wq = qkv_w[kk * 576 + qc], wk = qkv_w[kk * 576 + kc];
      #pragma unroll
      for (int i = 0; i < 4; ++i) { const float a = s_x[r0 + i][kk]; aq[i] += a * wq; ak[i] += a * wk; }
    }
    #pragma unroll
    for (int i = 0; i < 4; ++i) {
      s_q[r0 + i][c0] = (aq[i] + qkv_b[qc]) * SCALE;
      s_k[r0 + i][c0] = ak[i] + qkv_b[kc];
    }
    __syncthreads();
    {
      float ac[4] = {0,0,0,0};
      #pragma unroll
      for (int d = 0; d < 32; ++d) {
        const float kb = s_k[c0][d];
        #pragma unroll
        for (int i = 0; i < 4; ++i) ac[i] += s_q[r0 + i][d] * kb;
      }
      #pragma unroll
      for (int i = 0; i < 4; ++i) {
        const size_t g = ((size_t)(n * KW + r0 + i)) * KW + c0;
        const int* rp = rel_pos + 3 * g;
        float rpe = 0.f;
        #pragma unroll
        for (int a = 0; a < 3; ++a) {
          int ix = rp[a]; ix = ix < -25 ? -25 : (ix > 25 ? 25 : ix);
          rpe += rpe_table[(ix + 25 + 51 * a) * NH + h];
        }
        s_p[r0 + i][c0] = ac[i] + rpe + mask[g];
      }
    }
    __syncthreads();
    {
      const int r = tid >> 3, sb = tid & 7;
      float v0 = s_p[r][sb], v1 = s_p[r][sb + 8], v2 = s_p[r][sb + 16], v3 = s_p[r][sb + 24];
      float mx = fmaxf(fmaxf(v0, v1), fmaxf(v2, v3));
      mx = fmaxf(mx, __shfl_xor(mx, 1)); mx = fmaxf(mx, __shfl_xor(mx, 2)); mx = fmaxf(mx, __shfl_xor(mx, 4));
      v0 = __expf(v0 - mx); v1 = __expf(v1 - mx); v2 = __expf(v2 - mx); v3 = __expf(v3 - mx);
      float sm = v0 + v1 + v2 + v3;
      sm += __shfl_xor(sm, 1); sm += __shfl_xor(sm, 2); sm += __shfl_xor(sm, 4);
      const float inv = 1.0f / sm;
      s_p[r][sb] = v0 * inv; s_p[r][sb + 8] = v1 * inv; s_p[r][sb + 16] = v2 * inv; s_p[r][sb + 24] = v3 * inv;
    }
    __syncthreads();
    {
      const int vc = 2 * CD + h * 32 + c0;
      float av[4] = {0,0,0,0};
      for (int kk = 0; kk < CD; ++kk) {
        const float wvv = qkv_w[kk * 576 + vc];
        #pragma unroll
        for (int i = 0; i < 4; ++i) av[i] += s_x[r0 + i][kk] * wvv;
      }
      #pragma unroll
      for (int i = 0; i < 4; ++i) s_q[r0 + i][c0] = av[i] + qkv_b[vc];
    }
    __syncthreads();
    {
      float ao[4] = {0,0,0,0};
      #pragma unroll
      for (int j = 0; j < KW; ++j) {
        const float vb = s_q[j][c0];
        #pragma unroll
        for (int i = 0; i < 4; ++i) ao[i] += s_p[r0 + i][j] * vb;
      }
      #pragma unroll
      for (int i = 0; i < 4; ++i) s_ao[r0 + i][h * 32 + c0] = ao[i];
    }
    __syncthreads();
  }
  {
    float acc[4][6];
    #pragma unroll
    for (int j = 0; j < 6; ++j) {
      const float pb = proj_b[c0 + 32 * j];
      #pragma unroll
      for (int i = 0; i < 4; ++i) acc[i][j] = pb;
    }
    for (int kk = 0; kk < CD; ++kk) {
      float a[4];
      #pragma unroll
      for (int i = 0; i < 4; ++i) a[i] = s_ao[r0 + i][kk];
      #pragma unroll
      for (int j = 0; j < 6; ++j) {
        const float w = proj_w[kk * CD + c0 + 32 * j];
        #pragma unroll
        for (int i = 0; i < 4; ++i) acc[i][j] += a[i] * w;
      }
    }
    #pragma unroll
    for (int j = 0; j < 6; ++j)
      #pragma unroll
      for (int i = 0; i < 4; ++i) res[i][j] += acc[i][j];
  }
  __syncthreads();
  #pragma unroll
  for (int i = 0; i < 4; ++i) {
    float s = 0.f, q = 0.f;
    #pragma unroll
    for (int j = 0; j < 6; ++j) { s += res[i][j]; q += res[i][j] * res[i][j]; }
    #pragma unroll
    for (int m = 16; m >= 1; m >>= 1) { s += __shfl_xor(s, m); q += __shfl_xor(q, m); }
    const float mean = s / CD, rstd = rsqrtf(q / CD - mean * mean + 1e-5f);
    #pragma unroll
    for (int j = 0; j < 6; ++j) {
      const int c = c0 + 32 * j;
      s_x[r0 + i][c] = (res[i][j] - mean) * rstd * ln2_g[c] + ln2_b[c];
    }
  }
  __syncthreads();
  {
    float y[4][6];
    #pragma unroll
    for (int j = 0; j < 6; ++j) {
      const float bb = mlp_b2[c0 + 32 * j];
      #pragma unroll
      for (int i = 0; i < 4; ++i) y[i][j] = bb;
    }
    for (int cc = 0; cc < 4; ++cc) {
      {
        float acc[4][6];
        #pragma unroll
        for (int j = 0; j < 6; ++j) {
          const float b1 = mlp_b1[cc * CD + c0 + 32 * j];
          #pragma unroll
          for (int i = 0; i < 4; ++i) acc[i][j] = b1;
        }
        for (int kk = 0; kk < CD; ++kk) {
          float a[4];
          #pragma unroll
          for (int i = 0; i < 4; ++i) a[i] = s_x[r0 + i][kk];
          #pragma unroll
          for (int j = 0; j < 6; ++j) {
            const float w = mlp_w1[kk * HID + cc * CD + c0 + 32 * j];
            #pragma unroll
            for (int i = 0; i < 4; ++i) acc[i][j] += a[i] * w;
          }
        }
        #pragma unroll
        for (int j = 0; j < 6; ++j)
          #pragma unroll
          for (int i = 0; i < 4; ++i) {
            const float x = acc[i][j];
            s_ao[r0 + i][c0 + 32 * j] = 0.5f * x * (1.0f + erff(x * 0.70710678118654752f));
          }
      }
      __syncthreads();
      for (int kk = 0; kk < CD; ++kk) {
        float a[4];
        #pragma unroll
        for (int i = 0; i < 4; ++i) a[i] = s_ao[r0 + i][kk];
        #pragma unroll
        for (int j = 0; j < 6; ++j) {
          const float w = mlp_w2[(cc * CD + kk) * CD + c0 + 32 * j];
          #pragma unroll
          for (int i = 0; i < 4; ++i) y[i][j] += a[i] * w;
        }
      }
      __syncthreads();
    }
    #pragma unroll
    for (int i = 0; i < 4; ++i)
      #pragma unroll
      for (int j = 0; j < 6; ++j)
        out[base + (r0 + i) * CD + c0 + 32 * j] = res[i][j] + y[i][j];
  }
}

extern "C" void kernel_launch(void* const* d_in, const int* in_sizes, int n_in,
                              void* d_out, int out_size, void* d_ws, size_t ws_size,
                              hipStream_t stream) {
  (void)in_sizes; (void)n_in; (void)out_size;
  const float* data   = (const float*)d_in[0];
  const float* maskp  = (const float*)d_in[1];
  const int*   relp   = (const int*)d_in[2];
  const float* ln1g   = (const float*)d_in[3];
  const float* ln1b   = (const float*)d_in[4];
  const float* qkvw   = (const float*)d_in[5];
  const float* qkvb   = (const float*)d_in[6];
  const float* rpet   = (const float*)d_in[7];
  const float* projw  = (const float*)d_in[8];
  const float* projb  = (const float*)d_in[9];
  const float* ln2g   = (const float*)d_in[10];
  const float* ln2b   = (const float*)d_in[11];
  const float* mlpw1  = (const float*)d_in[12];
  const float* mlpb1  = (const float*)d_in[13];
  const float* mlpw2  = (const float*)d_in[14];
  const float* mlpb2  = (const float*)d_in[15];
  float* outp = (float*)d_out;

  if (ws_size >= (size_t)WS_BYTES) {
    u16* ws = (u16*)d_ws;
    pack_weights<<<dim3(NFRAG / 4), dim3(256), 0, stream>>>(qkvw, projw, mlpw1, mlpw2, ws);
    octformer_attn<<<dim3(4096), dim3(512), 0, stream>>>(
        data, maskp, relp, ln1g, ln1b, qkvb, rpet, projb, ws, outp);
    octformer_mlp<<<dim3(4096), dim3(512), 0, stream>>>(
        ln2g, ln2b, mlpb1, mlpb2, ws, outp);
  } else {
    octformer_scalar<<<dim3(8192), dim3(256), 0, stream>>>(
        data, maskp, relp, ln1g, ln1b, qkvw, qkvb, rpet, projw, projb,
        ln2g, ln2b, mlpw1, mlpb1, mlpw2, mlpb2, outp);
  }
}

// Round 5
// 1081.550 us; speedup vs baseline: 1.1406x; 1.0506x over previous
//
#include <hip/hip_runtime.h>
#include <hip/hip_bf16.h>
#include <cmath>

// OctFormer block on MI355X. Round 8.
// R7 post-mortem: split worked (attn: clean traffic 184/196 MB, VGPR 80,
// 478 us; mlp ~400 us) but attn occupancy stuck at 24% = 1x512thr block/CU.
// Unified register model: waves/SIMD = floor(512 / (archVGPR + AGPR)).
// attn: 80 + ~24 acc => ~104..136; evidently >128 without a cap -> 2 waves/SIMD.
// R4's (512,4) spill was because the FUSED kernel's arch demand > its share of
// the 128 cap; the split kernels' demand fits under 128.
// R8: __launch_bounds__(512, 4) on both kernels -> unified cap 128 ->
// 2 blocks/CU (50% occ). attn 80+24=104 fits; mlp ~70+48=118 fits (watch
// WRITE_SIZE for spill; revert per-kernel if it jumps).

#define KW    32
#define CD    192
#define NH    6
#define HID   768
#define SCALE 0.17677669529663687f

typedef short short8 __attribute__((ext_vector_type(8)));
typedef float f32x4  __attribute__((ext_vector_type(4)));
typedef unsigned short u16;

// fragment-pool bases (units: 1 fragment = 64 lanes * 8 bf16 = 512 elems)
#define FB_QKV  0     // 36 n-tiles * 6 kb
#define FB_PROJ 216   // 12 * 6
#define FB_MLP1 288   // 48 * 6
#define FB_MLP2 576   // 12 * 24
#define NFRAG   864
#define WS_BYTES (NFRAG * 512 * 2)

__device__ __forceinline__ u16 f2bb(float v) {
  __hip_bfloat16 h = __float2bfloat16(v);
  return *(u16*)&h;
}
__device__ __forceinline__ float bb2f(u16 b) {
  union { float f; unsigned u; } x; x.u = ((unsigned)b) << 16; return x.f;
}

// ---------------- weight pack: f32 row-major -> bf16 B-fragments ----------------
__global__ __launch_bounds__(256) void pack_weights(
    const float* __restrict__ qkv_w, const float* __restrict__ proj_w,
    const float* __restrict__ mlp_w1, const float* __restrict__ mlp_w2,
    u16* __restrict__ ws)
{
  const int idx  = blockIdx.x * 256 + threadIdx.x;   // 864*64 threads
  const int f    = idx >> 6;
  const int lane = idx & 63;
  const float* src; int N, KB, fl;
  if (f < FB_PROJ)      { src = qkv_w;  N = 576; KB = 6;  fl = f; }
  else if (f < FB_MLP1) { src = proj_w; N = 192; KB = 6;  fl = f - FB_PROJ; }
  else if (f < FB_MLP2) { src = mlp_w1; N = 768; KB = 6;  fl = f - FB_MLP1; }
  else                  { src = mlp_w2; N = 192; KB = 24; fl = f - FB_MLP2; }
  const int nt = fl / KB, kb = fl % KB;
  const int k0 = kb * 32 + (lane >> 4) * 8;
  const int n  = nt * 16 + (lane & 15);
  u16* dst = ws + ((size_t)(f * 64 + lane)) * 8;
  #pragma unroll
  for (int j = 0; j < 8; ++j) dst[j] = f2bb(src[(size_t)(k0 + j) * N + n]);
}

// ---------------- kernel A: LN1 + QKV + attention + proj + residual -> x2 ----------------
__global__ __launch_bounds__(512, 4) void octformer_attn(
    const float* __restrict__ data, const float* __restrict__ mask,
    const int* __restrict__ rel_pos,
    const float* __restrict__ ln1_g, const float* __restrict__ ln1_b,
    const float* __restrict__ qkv_b, const float* __restrict__ rpe_table,
    const float* __restrict__ proj_b,
    const u16* __restrict__ wsb, float* __restrict__ x2)
{
  // 64 rows (2 windows) x 192 cols; stride 200 bf16 = 400 B.
  __shared__ __align__(16) u16 s_x[64][200];    // LN1 out; later proj-out
  __shared__ __align__(16) u16 s_qkv[64][200];  // q | k | vt; P overlays q
  __shared__ __align__(16) u16 s_ao[64][200];   // attention output (proj A)

  const int tid  = threadIdx.x;
  const int n0   = blockIdx.x * 2;
  const size_t base = (size_t)blockIdx.x * (2 * KW * CD);

  const int wv   = tid >> 6;        // wave 0..7
  const int lane = tid & 63;
  const int l15  = lane & 15;
  const int quad = lane >> 4;

  const int rg = tid >> 5;          // elementwise rows rg*4..rg*4+3
  const int c0 = tid & 31;

  const int mh   = wv >> 2;         // GEMM: m-tiles {2mh, 2mh+1}
  const int nsub = wv & 3;          // GEMM: n-tiles {nsub, nsub+4, nsub+8}

  const int hh   = wv & 1;          // attention: head parity
  const int w_at = (wv >> 1) & 1;   // attention: window
  const int rth  = wv >> 2;         // attention: q row-tile

  const f32x4 zed = {0.f, 0.f, 0.f, 0.f};

  // ---- Phase 1: LN1 -> s_x (no residual registers kept) ----
  #pragma unroll
  for (int i = 0; i < 4; ++i) {
    const int r = rg * 4 + i;
    float v[6]; float s = 0.f, q = 0.f;
    #pragma unroll
    for (int j = 0; j < 6; ++j) {
      v[j] = data[base + r * CD + c0 + 32 * j];
      s += v[j]; q += v[j] * v[j];
    }
    #pragma unroll
    for (int m = 16; m >= 1; m >>= 1) { s += __shfl_xor(s, m); q += __shfl_xor(q, m); }
    const float mean = s * (1.0f / CD);
    const float rstd = rsqrtf(q * (1.0f / CD) - mean * mean + 1e-5f);
    #pragma unroll
    for (int j = 0; j < 6; ++j) {
      const int c = c0 + 32 * j;
      s_x[r][c] = f2bb((v[j] - mean) * rstd * ln1_g[c] + ln1_b[c]);
    }
  }

  // ---- preload packed RPE indices + mask bit for this wave's attention tile ----
  unsigned pidx[2][4];
  #pragma unroll
  for (int ct = 0; ct < 2; ++ct)
    #pragma unroll
    for (int i = 0; i < 4; ++i) {
      const int r = rth * 16 + quad * 4 + i;
      const int c = ct * 16 + l15;
      const size_t g = ((size_t)(n0 + w_at) * KW + r) * KW + c;
      const int* rp = rel_pos + 3 * g;
      int i0 = rp[0]; i0 = i0 < -25 ? -25 : (i0 > 25 ? 25 : i0); i0 += 25;
      int i1 = rp[1]; i1 = i1 < -25 ? -25 : (i1 > 25 ? 25 : i1); i1 += 76;
      int i2 = rp[2]; i2 = i2 < -25 ? -25 : (i2 > 25 ? 25 : i2); i2 += 127;
      const unsigned mb = (mask[g] < -0.5f) ? (1u << 24) : 0u;
      pidx[ct][i] = (unsigned)i0 | ((unsigned)i1 << 8) | ((unsigned)i2 << 16) | mb;
    }
  __syncthreads();

  // ---- Phase 2: head-pair loop ----
  for (int hp = 0; hp < 3; ++hp) {
    // (a) QKV GEMM for heads {2hp, 2hp+1}: 12 n-tiles x 4 m-tiles over 8 waves
    {
      f32x4 acc[3][2];
      #pragma unroll
      for (int ni = 0; ni < 3; ++ni)
        #pragma unroll
        for (int mi = 0; mi < 2; ++mi) acc[ni][mi] = zed;
      for (int kb = 0; kb < 6; ++kb) {
        short8 a[2];
        #pragma unroll
        for (int mi = 0; mi < 2; ++mi)
          a[mi] = *(const short8*)&s_x[(mh * 2 + mi) * 16 + l15][kb * 32 + quad * 8];
        #pragma unroll
        for (int ni = 0; ni < 3; ++ni) {
          const int gnt = ni * 12 + hp * 4 + nsub;
          const short8 b = *(const short8*)(wsb + ((size_t)((FB_QKV + gnt * 6 + kb) * 64 + lane)) * 8);
          #pragma unroll
          for (int mi = 0; mi < 2; ++mi)
            acc[ni][mi] = __builtin_amdgcn_mfma_f32_16x16x32_bf16(a[mi], b, acc[ni][mi], 0, 0, 0);
        }
      }
      #pragma unroll
      for (int ni = 0; ni < 3; ++ni) {
        const int gnt = ni * 12 + hp * 4 + nsub;
        const float bias = qkv_b[gnt * 16 + l15];
        if (ni < 2) {                        // q (scaled) and k: row-major
          #pragma unroll
          for (int mi = 0; mi < 2; ++mi)
            #pragma unroll
            for (int i = 0; i < 4; ++i) {
              float v = acc[ni][mi][i] + bias;
              if (ni == 0) v *= SCALE;
              s_qkv[(mh * 2 + mi) * 16 + quad * 4 + i][ni * 64 + nsub * 16 + l15] = f2bb(v);
            }
        } else {                             // v: write TRANSPOSED vt[d][key]
          const int vr = (nsub >> 1) * 32 + (nsub & 1) * 16 + l15;  // row = hv*32 + d
          #pragma unroll
          for (int mi = 0; mi < 2; ++mi)
            #pragma unroll
            for (int i = 0; i < 4; ++i) {
              const int gr = (mh * 2 + mi) * 16 + quad * 4 + i;     // global key row
              s_qkv[vr][128 + (gr >> 5) * 32 + (gr & 31)] = f2bb(acc[ni][mi][i] + bias);
            }
        }
      }
    }
    __syncthreads();

    // (b) attention: slab (w_at, head h=2hp+hh), row-tile rth; wave-local
    {
      const int h = hp * 2 + hh;
      const int rbase = w_at * 32;
      const short8 qf  = *(const short8*)&s_qkv[rbase + rth * 16 + l15][hh * 32 + quad * 8];
      const short8 kf0 = *(const short8*)&s_qkv[rbase + l15][64 + hh * 32 + quad * 8];
      const short8 kf1 = *(const short8*)&s_qkv[rbase + 16 + l15][64 + hh * 32 + quad * 8];
      const f32x4 sa0 = __builtin_amdgcn_mfma_f32_16x16x32_bf16(qf, kf0, zed, 0, 0, 0);
      const f32x4 sa1 = __builtin_amdgcn_mfma_f32_16x16x32_bf16(qf, kf1, zed, 0, 0, 0);
      float S0[4], S1[4];
      #pragma unroll
      for (int i = 0; i < 4; ++i) {
        unsigned p = pidx[0][i];
        float b = rpe_table[(p & 255u) * NH + h]
                + rpe_table[((p >> 8) & 255u) * NH + h]
                + rpe_table[((p >> 16) & 255u) * NH + h];
        if (p >> 24) b -= 1e9f;
        S0[i] = sa0[i] + b;
        p = pidx[1][i];
        b = rpe_table[(p & 255u) * NH + h]
          + rpe_table[((p >> 8) & 255u) * NH + h]
          + rpe_table[((p >> 16) & 255u) * NH + h];
        if (p >> 24) b -= 1e9f;
        S1[i] = sa1[i] + b;
      }
      // softmax over 32 keys; P bf16 overlays q cols (own slab region only)
      #pragma unroll
      for (int i = 0; i < 4; ++i) {
        float mx = fmaxf(S0[i], S1[i]);
        #pragma unroll
        for (int m = 8; m >= 1; m >>= 1) mx = fmaxf(mx, __shfl_xor(mx, m));
        const float e0 = __expf(S0[i] - mx);
        const float e1 = __expf(S1[i] - mx);
        float sm = e0 + e1;
        #pragma unroll
        for (int m = 8; m >= 1; m >>= 1) sm += __shfl_xor(sm, m);
        const float inv = 1.0f / sm;
        const int r = rbase + rth * 16 + quad * 4 + i;
        s_qkv[r][hh * 32 + l15]      = f2bb(e0 * inv);
        s_qkv[r][hh * 32 + 16 + l15] = f2bb(e1 * inv);
      }
      // O = P V  (V already transposed in LDS by QKV epilogue)
      const short8 pf  = *(const short8*)&s_qkv[rbase + rth * 16 + l15][hh * 32 + quad * 8];
      const short8 vf0 = *(const short8*)&s_qkv[hh * 32 + l15][128 + w_at * 32 + quad * 8];
      const short8 vf1 = *(const short8*)&s_qkv[hh * 32 + 16 + l15][128 + w_at * 32 + quad * 8];
      const f32x4 o0 = __builtin_amdgcn_mfma_f32_16x16x32_bf16(pf, vf0, zed, 0, 0, 0);
      const f32x4 o1 = __builtin_amdgcn_mfma_f32_16x16x32_bf16(pf, vf1, zed, 0, 0, 0);
      #pragma unroll
      for (int i = 0; i < 4; ++i) {
        const int r = rbase + rth * 16 + quad * 4 + i;
        s_ao[r][h * 32 + l15]      = f2bb(o0[i]);
        s_ao[r][h * 32 + 16 + l15] = f2bb(o1[i]);
      }
    }
    __syncthreads();
  }

  // ---- Phase 3: proj GEMM (A = s_ao) -> s_x (bf16, +bias) ----
  {
    f32x4 acc[3][2];
    #pragma unroll
    for (int ni = 0; ni < 3; ++ni)
      #pragma unroll
      for (int mi = 0; mi < 2; ++mi) acc[ni][mi] = zed;
    for (int kb = 0; kb < 6; ++kb) {
      short8 a[2];
      #pragma unroll
      for (int mi = 0; mi < 2; ++mi)
        a[mi] = *(const short8*)&s_ao[(mh * 2 + mi) * 16 + l15][kb * 32 + quad * 8];
      #pragma unroll
      for (int ni = 0; ni < 3; ++ni) {
        const int nt = nsub + 4 * ni;
        const short8 b = *(const short8*)(wsb + ((size_t)((FB_PROJ + nt * 6 + kb) * 64 + lane)) * 8);
        #pragma unroll
        for (int mi = 0; mi < 2; ++mi)
          acc[ni][mi] = __builtin_amdgcn_mfma_f32_16x16x32_bf16(a[mi], b, acc[ni][mi], 0, 0, 0);
      }
    }
    #pragma unroll
    for (int ni = 0; ni < 3; ++ni) {
      const int nt = nsub + 4 * ni;
      const float bias = proj_b[nt * 16 + l15];
      #pragma unroll
      for (int mi = 0; mi < 2; ++mi)
        #pragma unroll
        for (int i = 0; i < 4; ++i)
          s_x[(mh * 2 + mi) * 16 + quad * 4 + i][nt * 16 + l15] = f2bb(acc[ni][mi][i] + bias);
    }
  }
  __syncthreads();

  // ---- epilogue: x2 = data (re-read) + proj_out ----
  #pragma unroll
  for (int i = 0; i < 4; ++i) {
    const int r = rg * 4 + i;
    #pragma unroll
    for (int j = 0; j < 6; ++j) {
      const int c = c0 + 32 * j;
      x2[base + r * CD + c] = data[base + r * CD + c] + bb2f(s_x[r][c]);
    }
  }
}

// ---------------- kernel B: LN2 + MLP + residual (RMW on io = x2 -> final) ----------------
__global__ __launch_bounds__(512, 4) void octformer_mlp(
    const float* __restrict__ ln2_g, const float* __restrict__ ln2_b,
    const float* __restrict__ mlp_b1, const float* __restrict__ mlp_b2,
    const u16* __restrict__ wsb, float* __restrict__ io)
{
  __shared__ __align__(16) u16 s_x[64][200];   // LN2 out
  __shared__ __align__(16) u16 s_h[64][200];   // gelu hidden chunk

  const int tid  = threadIdx.x;
  const size_t base = (size_t)blockIdx.x * (64 * CD);

  const int wv   = tid >> 6;
  const int lane = tid & 63;
  const int l15  = lane & 15;
  const int quad = lane >> 4;

  const int rg = tid >> 5;
  const int c0 = tid & 31;

  const int mh   = wv >> 2;
  const int nsub = wv & 3;

  const f32x4 zed = {0.f, 0.f, 0.f, 0.f};

  // ---- Phase 1: LN2(x2) -> s_x ----
  #pragma unroll
  for (int i = 0; i < 4; ++i) {
    const int r = rg * 4 + i;
    float v[6]; float s = 0.f, q = 0.f;
    #pragma unroll
    for (int j = 0; j < 6; ++j) {
      v[j] = io[base + r * CD + c0 + 32 * j];
      s += v[j]; q += v[j] * v[j];
    }
    #pragma unroll
    for (int m = 16; m >= 1; m >>= 1) { s += __shfl_xor(s, m); q += __shfl_xor(q, m); }
    const float mean = s * (1.0f / CD);
    const float rstd = rsqrtf(q * (1.0f / CD) - mean * mean + 1e-5f);
    #pragma unroll
    for (int j = 0; j < 6; ++j) {
      const int c = c0 + 32 * j;
      s_x[r][c] = f2bb((v[j] - mean) * rstd * ln2_g[c] + ln2_b[c]);
    }
  }
  __syncthreads();

  // ---- Phase 2: MLP, hidden 768 in 4 chunks of 192 ----
  f32x4 y[3][2];
  #pragma unroll
  for (int ni = 0; ni < 3; ++ni)
    #pragma unroll
    for (int mi = 0; mi < 2; ++mi) y[ni][mi] = zed;

  for (int cc = 0; cc < 4; ++cc) {
    // mlp1 chunk: gelu(x @ w1 + b1) -> s_h bf16
    {
      f32x4 acc[3][2];
      #pragma unroll
      for (int ni = 0; ni < 3; ++ni)
        #pragma unroll
        for (int mi = 0; mi < 2; ++mi) acc[ni][mi] = zed;
      for (int kb = 0; kb < 6; ++kb) {
        short8 a[2];
        #pragma unroll
        for (int mi = 0; mi < 2; ++mi)
          a[mi] = *(const short8*)&s_x[(mh * 2 + mi) * 16 + l15][kb * 32 + quad * 8];
        #pragma unroll
        for (int ni = 0; ni < 3; ++ni) {
          const int gnt = cc * 12 + nsub + 4 * ni;
          const short8 b = *(const short8*)(wsb + ((size_t)((FB_MLP1 + gnt * 6 + kb) * 64 + lane)) * 8);
          #pragma unroll
          for (int mi = 0; mi < 2; ++mi)
            acc[ni][mi] = __builtin_amdgcn_mfma_f32_16x16x32_bf16(a[mi], b, acc[ni][mi], 0, 0, 0);
        }
      }
      #pragma unroll
      for (int ni = 0; ni < 3; ++ni) {
        const int lnt = nsub + 4 * ni;
        const float b1 = mlp_b1[(cc * 12 + lnt) * 16 + l15];
        #pragma unroll
        for (int mi = 0; mi < 2; ++mi)
          #pragma unroll
          for (int i = 0; i < 4; ++i) {
            const float v = acc[ni][mi][i] + b1;
            const float gel = 0.5f * v * (1.0f + erff(v * 0.70710678118654752f));
            s_h[(mh * 2 + mi) * 16 + quad * 4 + i][lnt * 16 + l15] = f2bb(gel);
          }
      }
    }
    __syncthreads();

    // mlp2 chunk: y += h_chunk @ w2[cc]
    for (int kb = 0; kb < 6; ++kb) {
      short8 a[2];
      #pragma unroll
      for (int mi = 0; mi < 2; ++mi)
        a[mi] = *(const short8*)&s_h[(mh * 2 + mi) * 16 + l15][kb * 32 + quad * 8];
      #pragma unroll
      for (int ni = 0; ni < 3; ++ni) {
        const int nt = nsub + 4 * ni;
        const short8 b = *(const short8*)(wsb + ((size_t)((FB_MLP2 + nt * 24 + cc * 6 + kb) * 64 + lane)) * 8);
        #pragma unroll
        for (int mi = 0; mi < 2; ++mi)
          y[ni][mi] = __builtin_amdgcn_mfma_f32_16x16x32_bf16(a[mi], b, y[ni][mi], 0, 0, 0);
      }
    }
    __syncthreads();
  }

  // ---- epilogue: io = x2 + y + b2 (direct global RMW in MFMA layout) ----
  #pragma unroll
  for (int ni = 0; ni < 3; ++ni) {
    const int nt = nsub + 4 * ni;
    const float b2 = mlp_b2[nt * 16 + l15];
    #pragma unroll
    for (int mi = 0; mi < 2; ++mi)
      #pragma unroll
      for (int i = 0; i < 4; ++i) {
        const size_t g = base + (size_t)((mh * 2 + mi) * 16 + quad * 4 + i) * CD + nt * 16 + l15;
        io[g] = io[g] + y[ni][mi][i] + b2;
      }
  }
}

// ---------------- scalar fallback (R2 float path) if ws too small ----------------
__global__ __launch_bounds__(256) void octformer_scalar(
    const float* __restrict__ data, const float* __restrict__ mask, const int* __restrict__ rel_pos,
    const float* __restrict__ ln1_g, const float* __restrict__ ln1_b,
    const float* __restrict__ qkv_w, const float* __restrict__ qkv_b, const float* __restrict__ rpe_table,
    const float* __restrict__ proj_w, const float* __restrict__ proj_b,
    const float* __restrict__ ln2_g, const float* __restrict__ ln2_b,
    const float* __restrict__ mlp_w1, const float* __restrict__ mlp_b1,
    const float* __restrict__ mlp_w2, const float* __restrict__ mlp_b2,
    float* __restrict__ out)
{
  const int n = blockIdx.x, tid = threadIdx.x;
  __shared__ float s_x[KW][CD];
  __shared__ float s_ao[KW][CD];
  __shared__ float s_q[KW][33];
  __shared__ float s_k[KW][33];
  __shared__ float s_p[KW][33];
  const size_t base = (size_t)n * (KW * CD);
  const int r0 = (tid >> 5) << 2, c0 = tid & 31;
  float res[4][6];
  #pragma unroll
  for (int i = 0; i < 4; ++i)
    #pragma unroll
    for (int j = 0; j < 6; ++j) res[i][j] = data[base + (r0 + i) * CD + c0 + 32 * j];
  #pragma unroll
  for (int i = 0; i < 4; ++i) {
    float s = 0.f, q = 0.f;
    #pragma unroll
    for (int j = 0; j < 6; ++j) { s += res[i][j]; q += res[i][j] * res[i][j]; }
    #pragma unroll
    for (int m = 16; m >= 1; m >>= 1) { s += __shfl_xor(s, m); q += __shfl_xor(q, m); }
    const float mean = s / CD, rstd = rsqrtf(q / CD - mean * mean + 1e-5f);
    #pragma unroll
    for (int j = 0; j < 6; ++j) {
      const int c = c0 + 32 * j;
      s_x[r0 + i][c] = (res[i][j] - mean) * rstd * ln1_g[c] + ln1_b[c];
    }
  }
  __syncthreads();
  for (int h = 0; h < NH; ++h) {
    const int qc = h * 32 + c0, kc = CD + h * 32 + c0;
    float aq[4] = {0,0,0,0}, ak[4] = {0,0,0,0};
    for (int kk = 0; kk < CD; ++kk) {
      const float wq = qkv_w[kk * 576 + qc], wk = qkv_w[kk * 576 + kc];
      #pragma unroll
      for (int i = 0; i < 4; ++i) { const float a = s_x[r0 + i][kk]; aq[i] += a * wq; ak[i] += a * wk; }
    }
    #pragma unroll
    for (int i = 0; i < 4; ++i) {
      s_q[r0 + i][c0] = (aq[i] + qkv_b[qc]) * SCALE;
      s_k[r0 + i][c0] = ak[i] + qkv_b[kc];
    }
    __syncthreads();
    {
      float ac[4] = {0,0,0,0};
      #pragma unroll
      for (int d = 0; d < 32; ++d) {
        const float kb = s_k[c0][d];
        #pragma unroll
        for (int i = 0; i < 4; ++i) ac[i] += s_q[r0 + i][d] * kb;
      }
      #pragma unroll
      for (int i = 0; i < 4; ++i) {
        const size_t g = ((size_t)(n * KW + r0 + i)) * KW + c0;
        const int* rp = rel_pos + 3 * g;
        float rpe = 0.f;
        #pragma unroll
        for (int a = 0; a < 3; ++a) {
          int ix = rp[a]; ix = ix < -25 ? -25 : (ix > 25 ? 25 : ix);
          rpe += rpe_table[(ix + 25 + 51 * a) * NH + h];
        }
        s_p[r0 + i][c0] = ac[i] + rpe + mask[g];
      }
    }
    __syncthreads();
    {
      const int r = tid >> 3, sb = tid & 7;
      float v0 = s_p[r][sb], v1 = s_p[r][sb + 8], v2 = s_p[r][sb + 16], v3 = s_p[r][sb + 24];
      float mx = fmaxf(fmaxf(v0, v1), fmaxf(v2, v3));
      mx = fmaxf(mx, __shfl_xor(mx, 1)); mx = fmaxf(mx, __shfl_xor(mx, 2)); mx = fmaxf(mx, __shfl_xor(mx, 4));
      v0 = __expf(v0 - mx); v1 = __expf(v1 - mx); v2 = __expf(v2 - mx); v3 = __expf(v3 - mx);
      float sm = v0 + v1 + v2 + v3;
      sm += __shfl_xor(sm, 1); sm += __shfl_xor(sm, 2); sm += __shfl_xor(sm, 4);
      const float inv = 1.0f / sm;
      s_p[r][sb] = v0 * inv; s_p[r][sb + 8] = v1 * inv; s_p[r][sb + 16] = v2 * inv; s_p[r][sb + 24] = v3 * inv;
    }
    __syncthreads();
    {
      const int vc = 2 * CD + h * 32 + c0;
      float av[4] = {0,0,0,0};
      for (int kk = 0; kk < CD; ++kk) {
        const float wvv = qkv_w[kk * 576 + vc];
        #pragma unroll
        for (int i = 0; i < 4; ++i) av[i] += s_x[r0 + i][kk] * wvv;
      }
      #pragma unroll
      for (int i = 0; i < 4; ++i) s_q[r0 + i][c0] = av[i] + qkv_b[vc];
    }
    __syncthreads();
    {
      float ao[4] = {0,0,0,0};
      #pragma unroll
      for (int j = 0; j < KW; ++j) {
        const float vb = s_q[j][c0];
        #pragma unroll
        for (int i = 0; i < 4; ++i) ao[i] += s_p[r0 + i][j] * vb;
      }
      #pragma unroll
      for (int i = 0; i < 4; ++i) s_ao[r0 + i][h * 32 + c0] = ao[i];
    }
    __syncthreads();
  }
  {
    float acc[4][6];
    #pragma unroll
    for (int j = 0; j < 6; ++j) {
      const float pb = proj_b[c0 + 32 * j];
      #pragma unroll
      for (int i = 0; i < 4; ++i) acc[i][j] = pb;
    }
    for (int kk = 0; kk < CD; ++kk) {
      float a[4];
      #pragma unroll
      for (int i = 0; i < 4; ++i) a[i] = s_ao[r0 + i][kk];
      #pragma unroll
      for (int j = 0; j < 6; ++j) {
        const float w = proj_w[kk * CD + c0 + 32 * j];
        #pragma unroll
        for (int i = 0; i < 4; ++i) acc[i][j] += a[i] * w;
      }
    }
    #pragma unroll
    for (int j = 0; j < 6; ++j)
      #pragma unroll
      for (int i = 0; i < 4; ++i) res[i][j] += acc[i][j];
  }
  __syncthreads();
  #pragma unroll
  for (int i = 0; i < 4; ++i) {
    float s = 0.f, q = 0.f;
    #pragma unroll
    for (int j = 0; j < 6; ++j) { s += res[i][j]; q += res[i][j] * res[i][j]; }
    #pragma unroll
    for (int m = 16; m >= 1; m >>= 1) { s += __shfl_xor(s, m); q += __shfl_xor(q, m); }
    const float mean = s / CD, rstd = rsqrtf(q / CD - mean * mean + 1e-5f);
    #pragma unroll
    for (int j = 0; j < 6; ++j) {
      const int c = c0 + 32 * j;
      s_x[r0 + i][c] = (res[i][j] - mean) * rstd * ln2_g[c] + ln2_b[c];
    }
  }
  __syncthreads();
  {
    float y[4][6];
    #pragma unroll
    for (int j = 0; j < 6; ++j) {
      const float bb = mlp_b2[c0 + 32 * j];
      #pragma unroll
      for (int i = 0; i < 4; ++i) y[i][j] = bb;
    }
    for (int cc = 0; cc < 4; ++cc) {
      {
        float acc[4][6];
        #pragma unroll
        for (int j = 0; j < 6; ++j) {
          const float b1 = mlp_b1[cc * CD + c0 + 32 * j];
          #pragma unroll
          for (int i = 0; i < 4; ++i) acc[i][j] = b1;
        }
        for (int kk = 0; kk < CD; ++kk) {
          float a[4];
          #pragma unroll
          for (int i = 0; i < 4; ++i) a[i] = s_x[r0 + i][kk];
          #pragma unroll
          for (int j = 0; j < 6; ++j) {
            const float w = mlp_w1[kk * HID + cc * CD + c0 + 32 * j];
            #pragma unroll
            for (int i = 0; i < 4; ++i) acc[i][j] += a[i] * w;
          }
        }
        #pragma unroll
        for (int j = 0; j < 6; ++j)
          #pragma unroll
          for (int i = 0; i < 4; ++i) {
            const float x = acc[i][j];
            s_ao[r0 + i][c0 + 32 * j] = 0.5f * x * (1.0f + erff(x * 0.70710678118654752f));
          }
      }
      __syncthreads();
      for (int kk = 0; kk < CD; ++kk) {
        float a[4];
        #pragma unroll
        for (int i = 0; i < 4; ++i) a[i] = s_ao[r0 + i][kk];
        #pragma unroll
        for (int j = 0; j < 6; ++j) {
          const float w = mlp_w2[(cc * CD + kk) * CD + c0 + 32 * j];
          #pragma unroll
          for (int i = 0; i < 4; ++i) y[i][j] += a[i] * w;
        }
      }
      __syncthreads();
    }
    #pragma unroll
    for (int i = 0; i < 4; ++i)
      #pragma unroll
      for (int j = 0; j < 6; ++j)
        out[base + (r0 + i) * CD + c0 + 32 * j] = res[i][j] + y[i][j];
  }
}

extern "C" void kernel_launch(void* const* d_in, const int* in_sizes, int n_in,
                              void* d_out, int out_size, void* d_ws, size_t ws_size,
                              hipStream_t stream) {
  (void)in_sizes; (void)n_in; (void)out_size;
  const float* data   = (const float*)d_in[0];
  const float* maskp  = (const float*)d_in[1];
  const int*   relp   = (const int*)d_in[2];
  const float* ln1g   = (const float*)d_in[3];
  const float* ln1b   = (const float*)d_in[4];
  const float* qkvw   = (const float*)d_in[5];
  const float* qkvb   = (const float*)d_in[6];
  const float* rpet   = (const float*)d_in[7];
  const float* projw  = (const float*)d_in[8];
  const float* projb  = (const float*)d_in[9];
  const float* ln2g   = (const float*)d_in[10];
  const float* ln2b   = (const float*)d_in[11];
  const float* mlpw1  = (const float*)d_in[12];
  const float* mlpb1  = (const float*)d_in[13];
  const float* mlpw2  = (const float*)d_in[14];
  const float* mlpb2  = (const float*)d_in[15];
  float* outp = (float*)d_out;

  if (ws_size >= (size_t)WS_BYTES) {
    u16* ws = (u16*)d_ws;
    pack_weights<<<dim3(NFRAG / 4), dim3(256), 0, stream>>>(qkvw, projw, mlpw1, mlpw2, ws);
    octformer_attn<<<dim3(4096), dim3(512), 0, stream>>>(
        data, maskp, relp, ln1g, ln1b, qkvb, rpet, projb, ws, outp);
    octformer_mlp<<<dim3(4096), dim3(512), 0, stream>>>(
        ln2g, ln2b, mlpb1, mlpb2, ws, outp);
  } else {
    octformer_scalar<<<dim3(8192), dim3(256), 0, stream>>>(
        data, maskp, relp, ln1g, ln1b, qkvw, qkvb, rpet, projw, projb,
        ln2g, ln2b, mlpw1, mlpb1, mlpw2, mlpb2, outp);
  }
}